// Round 4
// baseline (788.479 us; speedup 1.0000x reference)
//
#include <hip/hip_runtime.h>

typedef unsigned short u16;
typedef unsigned int   u32;
typedef __attribute__((ext_vector_type(8))) short short8;
typedef __attribute__((ext_vector_type(4))) float floatx4;

#define N_B  16
#define N_S  1024
#define N_E  8192
#define N_D  512
#define N_H  8
#define N_DK 64
#define N_L  2
#define N_N  (N_B*N_S)   /* 16384 */
#define N_BE (N_B*N_E)   /* 131072 */

__device__ __forceinline__ float bf2f(u16 u){ return __uint_as_float(((u32)u)<<16); }
__device__ __forceinline__ u16 f2bf(float f){
  u32 i = __float_as_uint(f);
  return (u16)((i + 0x7fffu + ((i>>16)&1u)) >> 16);
}

/* ---------------- generic zero ---------------- */
__global__ void zero_kernel(u32* __restrict__ p, int n){
  int i = blockIdx.x*blockDim.x + threadIdx.x;
  if (i < n) p[i] = 0;
}

/* ---------------- fp32 -> bf16 convert (4 elems/thread) ---------------- */
__global__ void convert_kernel(const float* __restrict__ in, u16* __restrict__ outp, int n4){
  int i = blockIdx.x*blockDim.x + threadIdx.x;
  if (i < n4){
    float4 f = ((const float4*)in)[i];
    u16 o[4] = { f2bf(f.x), f2bf(f.y), f2bf(f.z), f2bf(f.w) };
    ((uint2*)outp)[i] = *(uint2*)o;
  }
}

/* ---- transpose+convert the 8 weight matrices (512x512 fp32) to bf16 N x K ----
   z = w*2 + l ; w: 0=Wq 1=Wk 2=Wv 3=Wo. out[n*512+k] = bf16(in[k*512+n]) */
__global__ void transpose_kernel(const float* __restrict__ Wq, const float* __restrict__ Wk,
                                 const float* __restrict__ Wv, const float* __restrict__ Wo,
                                 u16* __restrict__ WT){
  __shared__ u16 tile[32][33];
  int z = blockIdx.z, wsel = z>>1, l = z&1;
  const float* in = (wsel==0?Wq: wsel==1?Wk: wsel==2?Wv:Wo) + l*262144;
  u16* outp = WT + z*262144;
  int bx = blockIdx.x*32, by = blockIdx.y*32;
  int tx = threadIdx.x, ty = threadIdx.y;           /* block (32,8) */
  for (int r=0;r<32;r+=8) tile[ty+r][tx] = f2bf(in[(by+ty+r)*512 + bx+tx]);
  __syncthreads();
  for (int r=0;r<32;r+=8) outp[(bx+ty+r)*512 + by+tx] = tile[tx][ty+r];
}

/* ---------------- ragged-edge prefix over batches ---------------- */
__global__ void bstart_kernel(const int* __restrict__ edge_len, int* __restrict__ bstart){
  if (threadIdx.x==0 && blockIdx.x==0){
    int s=0;
    for (int b=0;b<N_B;b++){ bstart[b]=s; s+=edge_len[b]; }
    bstart[N_B]=s;
  }
}

/* ---------------- flatten ragged edges + in-degree count ---------------- */
__global__ void scatter_kernel(const int* __restrict__ edge_len, const int* __restrict__ edge_index,
                               const int* __restrict__ relpos_e, const int* __restrict__ deprel_e,
                               const int* __restrict__ deparc_e, const int* __restrict__ bstart,
                               int* __restrict__ src, int* __restrict__ tgt,
                               int* __restrict__ dr, int* __restrict__ da, int* __restrict__ rp,
                               int* __restrict__ deg){
  int idx = blockIdx.x*256 + threadIdx.x;           /* over B*E */
  int b = idx >> 13, e = idx & (N_E-1);
  if (e < edge_len[b]){
    int f = bstart[b] + e;
    int s = edge_index[idx*2+0] + b*N_S;
    int t = edge_index[idx*2+1] + b*N_S;
    src[f]=s; tgt[f]=t;
    dr[f]=deprel_e[idx]; da[f]=deparc_e[idx]; rp[f]=relpos_e[idx];
    atomicAdd(&deg[t], 1);
  }
}

/* ---------------- exclusive scan of degrees (N = 16384 = 1024*16) ---------------- */
__global__ void scan_kernel(const int* __restrict__ deg, int* __restrict__ row_start){
  __shared__ int sums[1024];
  int t = threadIdx.x;
  int base = t*16;
  int local[16]; int s = 0;
  for (int i=0;i<16;i++){ local[i] = s; s += deg[base+i]; }
  sums[t] = s; __syncthreads();
  for (int off=1; off<1024; off<<=1){
    int add = (t >= off) ? sums[t-off] : 0;
    __syncthreads();
    sums[t] += add;
    __syncthreads();
  }
  int prefix = (t>0) ? sums[t-1] : 0;
  for (int i=0;i<16;i++) row_start[base+i] = prefix + local[i];
  if (t==1023) row_start[N_N] = sums[1023];
}

/* ---------------- fill CSR edge lists ---------------- */
__global__ void fill_kernel(const int* __restrict__ edge_len, const int* __restrict__ bstart,
                            const int* __restrict__ tgt, const int* __restrict__ row_start,
                            int* __restrict__ cursor, int* __restrict__ edge_list){
  int idx = blockIdx.x*256 + threadIdx.x;
  int b = idx >> 13, e = idx & (N_E-1);
  if (e < edge_len[b]){
    int f = bstart[b]+e;
    int t = tgt[f];
    int pos = atomicAdd(&cursor[t], 1);
    edge_list[row_start[t]+pos] = f;
  }
}

/* ---- MFMA GEMM: C[M,512] = A[M,512] @ W ; A bf16, Bt is W^T bf16 (N x K row-major) ----
   M=16384, K=512, Nout=512. 128x128x32 tiles, 4 waves (2x2), each 64x64 via 4x4 16x16x32 */
template<bool F32OUT>
__global__ __launch_bounds__(256) void gemm_kernel(const u16* __restrict__ A,
    const u16* __restrict__ B0, const u16* __restrict__ B1, const u16* __restrict__ B2,
    void* __restrict__ C0, void* __restrict__ C1, void* __restrict__ C2){
  const u16* Bt = (blockIdx.z==0) ? B0 : (blockIdx.z==1) ? B1 : B2;
  void* C      = (blockIdx.z==0) ? C0 : (blockIdx.z==1) ? C1 : C2;
  __shared__ __align__(16) u16 As[128][40];   /* +8 pad: 16B-aligned rows */
  __shared__ __align__(16) u16 Bs[128][40];
  int tid  = threadIdx.x;
  int lane = tid & 63, wave = tid >> 6;
  int wm = wave >> 1, wn = wave & 1;
  int quad = lane >> 4, l16 = lane & 15;
  int tileM = blockIdx.y * 128, tileN = blockIdx.x * 128;

  floatx4 acc[4][4];
  for (int i=0;i<4;i++) for (int j=0;j<4;j++) acc[i][j] = (floatx4){0.f,0.f,0.f,0.f};

  for (int k0 = 0; k0 < 512; k0 += 32){
    __syncthreads();
    for (int r = 0; r < 2; r++){
      int c = r*256 + tid;          /* 512 chunks of 16B per tile */
      int row = c >> 2, cc = c & 3;
      *(int4*)&As[row][cc*8] = *(const int4*)&A [(size_t)(tileM+row)*512 + k0 + cc*8];
      *(int4*)&Bs[row][cc*8] = *(const int4*)&Bt[(size_t)(tileN+row)*512 + k0 + cc*8];
    }
    __syncthreads();
    short8 af[4], bfr[4];
    for (int i=0;i<4;i++) af [i] = *(const short8*)&As[wm*64 + i*16 + l16][quad*8];
    for (int j=0;j<4;j++) bfr[j] = *(const short8*)&Bs[wn*64 + j*16 + l16][quad*8];
    for (int i=0;i<4;i++)
      for (int j=0;j<4;j++)
        acc[i][j] = __builtin_amdgcn_mfma_f32_16x16x32_bf16(af[i], bfr[j], acc[i][j], 0,0,0);
  }
  /* C/D layout: col = lane&15, row = quad*4 + reg */
  for (int i=0;i<4;i++)
    for (int j=0;j<4;j++)
      for (int r=0;r<4;r++){
        int row = tileM + wm*64 + i*16 + quad*4 + r;
        int col = tileN + wn*64 + j*16 + l16;
        if (F32OUT) ((float*)C)[(size_t)row*512 + col] = acc[i][j][r];
        else        ((u16*) C)[(size_t)row*512 + col] = f2bf(acc[i][j][r]);
      }
}

/* ---- edge attention: one wave per (node, head), lane = DK dim ---- */
__global__ __launch_bounds__(256) void edge_attn_kernel(
    const u16* __restrict__ q, const u16* __restrict__ k, const u16* __restrict__ v,
    const int* __restrict__ row_start, const int* __restrict__ edge_list,
    const int* __restrict__ src, const int* __restrict__ dr, const int* __restrict__ da,
    const int* __restrict__ rp,
    const float* __restrict__ deprel_emb, const float* __restrict__ deparc_emb,
    const float* __restrict__ relpos_emb,
    u16* __restrict__ agg, float* __restrict__ attn_out){
  int wid  = (blockIdx.x*blockDim.x + threadIdx.x) >> 6;
  int lane = threadIdx.x & 63;
  int t = wid >> 3, h = wid & 7;
  int rs = row_start[t], re = row_start[t+1];
  float qd = bf2f(q[(size_t)t*512 + h*64 + lane]);

  float m = -1e30f, s = 0.f;
  for (int idx = rs; idx < re; idx++){
    int f = edge_list[idx];
    int sn = src[f];
    float kd  = bf2f(k[(size_t)sn*512 + h*64 + lane]);
    float rel = deprel_emb[dr[f]*64 + lane] + deparc_emb[da[f]*64 + lane]
              + relpos_emb[rp[f]*64 + lane];
    float p = qd * (kd + rel);
    for (int o=32;o>0;o>>=1) p += __shfl_xor(p, o);
    float logit = p * 0.125f;                 /* 1/sqrt(64) */
    float nm = fmaxf(m, logit);
    s = s*__expf(m-nm) + __expf(logit-nm);
    m = nm;
  }
  float invden = 1.f / (s + 1e-9f);

  float acc = 0.f;
  for (int idx = rs; idx < re; idx++){
    int f = edge_list[idx];
    int sn = src[f];
    float rel = deprel_emb[dr[f]*64 + lane] + deparc_emb[da[f]*64 + lane]
              + relpos_emb[rp[f]*64 + lane];
    float kd  = bf2f(k[(size_t)sn*512 + h*64 + lane]);
    float p = qd * (kd + rel);                /* recompute logit */
    for (int o=32;o>0;o>>=1) p += __shfl_xor(p, o);
    float alpha = __expf(p*0.125f - m) * invden;
    if (lane==0) attn_out[(size_t)f*8 + h] = alpha;
    float vd = bf2f(v[(size_t)sn*512 + h*64 + lane]);
    acc += alpha * (vd + rel);
  }
  agg[(size_t)t*512 + h*64 + lane] = f2bf(acc);
}

/* ---- residual + LayerNorm (+ReLU), wave per row of 512; writes fp32 reps + bf16 hb ---- */
__global__ __launch_bounds__(256) void ln_kernel(const float* __restrict__ out_pre,
    const float* __restrict__ h_in, const float* __restrict__ gamma,
    const float* __restrict__ beta,
    float* __restrict__ outf, u16* __restrict__ hb, int do_relu){
  int wid  = (blockIdx.x*blockDim.x + threadIdx.x) >> 6;   /* row */
  int lane = threadIdx.x & 63;
  const float* xp = out_pre + (size_t)wid*512;
  const float* hp = h_in    + (size_t)wid*512;
  float x[8]; float sum = 0.f;
  for (int i=0;i<8;i++){ int c = lane + i*64; x[i] = xp[c] + hp[c]; sum += x[i]; }
  for (int o=32;o>0;o>>=1) sum += __shfl_xor(sum, o);
  float mu = sum * (1.f/512.f);
  float vs = 0.f;
  for (int i=0;i<8;i++){ float d = x[i]-mu; vs += d*d; }
  for (int o=32;o>0;o>>=1) vs += __shfl_xor(vs, o);
  float inv = rsqrtf(vs*(1.f/512.f) + 1e-5f);
  for (int i=0;i<8;i++){
    int c = lane + i*64;
    float y = (x[i]-mu)*inv*gamma[c] + beta[c];
    if (do_relu) y = fmaxf(y, 0.f);
    outf[(size_t)wid*512 + c] = y;
    hb  [(size_t)wid*512 + c] = f2bf(y);
  }
}

extern "C" void kernel_launch(void* const* d_in, const int* in_sizes, int n_in,
                              void* d_out, int out_size, void* d_ws, size_t ws_size,
                              hipStream_t stream){
  (void)in_sizes; (void)n_in; (void)out_size; (void)ws_size;
  const float* inp      = (const float*)d_in[0];
  const int* edge_len   = (const int*)d_in[2];
  const int* edge_index = (const int*)d_in[3];
  const int* relpos_e   = (const int*)d_in[4];
  const int* deprel_e   = (const int*)d_in[6];
  const int* deparc_e   = (const int*)d_in[7];
  const float* Wq = (const float*)d_in[14];
  const float* Wk = (const float*)d_in[15];
  const float* Wv = (const float*)d_in[16];
  const float* Wo = (const float*)d_in[17];
  const float* deprel_emb = (const float*)d_in[18];
  const float* deparc_emb = (const float*)d_in[19];
  const float* relpos_emb = (const float*)d_in[20];
  const float* ln_scale   = (const float*)d_in[21];
  const float* ln_bias    = (const float*)d_in[22];
  float* outp = (float*)d_out;

  /* ---- carve workspace (~88 MB) ---- */
  char* w = (char*)d_ws;
  auto carve = [&](size_t b)->char*{ char* p = w; w += (b + 255) & ~(size_t)255; return p; };
  u16* WT        = (u16*)carve((size_t)8*262144*2);
  int* bstart    = (int*)carve(32*4);
  int* src       = (int*)carve((size_t)N_BE*4);
  int* tgt       = (int*)carve((size_t)N_BE*4);
  int* dr        = (int*)carve((size_t)N_BE*4);
  int* da        = (int*)carve((size_t)N_BE*4);
  int* rp        = (int*)carve((size_t)N_BE*4);
  int* deg       = (int*)carve((size_t)N_N*4);
  int* cursor    = (int*)carve((size_t)N_N*4);
  int* row_start = (int*)carve((size_t)(N_N+1)*4);
  int* edge_list = (int*)carve((size_t)N_BE*4);
  u16* hb        = (u16*)carve((size_t)N_N*512*2);
  u16* qb        = (u16*)carve((size_t)N_N*512*2);   /* qb+kb also alias out_pre (fp32) */
  u16* kb        = (u16*)carve((size_t)N_N*512*2);
  u16* vb        = (u16*)carve((size_t)N_N*512*2);
  u16* aggb      = (u16*)carve((size_t)N_N*512*2);
  float* out_pre = (float*)qb;   /* 32MB alias over qb+kb, dead by the time it's written */

  /* ---- per-call setup ---- */
  transpose_kernel<<<dim3(16,16,8), dim3(32,8), 0, stream>>>(Wq,Wk,Wv,Wo, WT);
  convert_kernel<<<dim3(8192), dim3(256), 0, stream>>>(inp, hb, N_N*512/4);
  zero_kernel<<<dim3(64),   dim3(256), 0, stream>>>((u32*)deg,    N_N);
  zero_kernel<<<dim3(64),   dim3(256), 0, stream>>>((u32*)cursor, N_N);
  u32* attn_all = (u32*)(outp + (size_t)N_L*N_N*512);
  zero_kernel<<<dim3(8192), dim3(256), 0, stream>>>(attn_all, N_L*N_BE*N_H);
  bstart_kernel<<<dim3(1), dim3(1), 0, stream>>>(edge_len, bstart);
  scatter_kernel<<<dim3(N_BE/256), dim3(256), 0, stream>>>(edge_len, edge_index,
      relpos_e, deprel_e, deparc_e, bstart, src, tgt, dr, da, rp, deg);
  scan_kernel<<<dim3(1), dim3(1024), 0, stream>>>(deg, row_start);
  fill_kernel<<<dim3(N_BE/256), dim3(256), 0, stream>>>(edge_len, bstart, tgt,
      row_start, cursor, edge_list);

  /* ---- layers ---- */
  for (int l=0; l<N_L; l++){
    const float* h_res = (l==0) ? inp : (outp);     /* residual input, fp32 */
    float* reps_out = outp + (size_t)l*N_N*512;
    float* attn_out = outp + (size_t)N_L*N_N*512 + (size_t)l*N_BE*N_H;
    const u16* WqT = WT + (0*2 + l)*262144;
    const u16* WkT = WT + (1*2 + l)*262144;
    const u16* WvT = WT + (2*2 + l)*262144;
    const u16* WoT = WT + (3*2 + l)*262144;

    gemm_kernel<false><<<dim3(4,128,3), dim3(256), 0, stream>>>(hb,
        WqT, WkT, WvT, (void*)qb, (void*)kb, (void*)vb);

    edge_attn_kernel<<<dim3(N_N*N_H/4), dim3(256), 0, stream>>>(qb, kb, vb,
        row_start, edge_list, src, dr, da, rp,
        deprel_emb + l*50*64, deparc_emb + l*3*64, relpos_emb + l*21*64,
        aggb, attn_out);

    gemm_kernel<true><<<dim3(4,128,1), dim3(256), 0, stream>>>(aggb,
        WoT, WoT, WoT, (void*)out_pre, (void*)out_pre, (void*)out_pre);

    ln_kernel<<<dim3(N_N/4), dim3(256), 0, stream>>>(out_pre,
        (l==0) ? inp : outp,            /* residual: inp or reps[0] */
        ln_scale + l*512, ln_bias + l*512, reps_out, hb, (l==0)?1:0);
  }
}

// Round 5
// 465.145 us; speedup vs baseline: 1.6951x; 1.6951x over previous
//
#include <hip/hip_runtime.h>

typedef unsigned short u16;
typedef unsigned int   u32;
typedef __attribute__((ext_vector_type(8))) short short8;
typedef __attribute__((ext_vector_type(4))) float floatx4;

#define N_B  16
#define N_S  1024
#define N_E  8192
#define N_D  512
#define N_H  8
#define N_DK 64
#define N_L  2
#define N_N  (N_B*N_S)   /* 16384 */
#define N_BE (N_B*N_E)   /* 131072 */

__device__ __forceinline__ float bf2f(u16 u){ return __uint_as_float(((u32)u)<<16); }
__device__ __forceinline__ u16 f2bf(float f){
  u32 i = __float_as_uint(f);
  return (u16)((i + 0x7fffu + ((i>>16)&1u)) >> 16);
}

/* ---------------- generic zero ---------------- */
__global__ void zero_kernel(u32* __restrict__ p, int n){
  int i = blockIdx.x*blockDim.x + threadIdx.x;
  if (i < n) p[i] = 0;
}

/* ---------------- fp32 -> bf16 convert (4 elems/thread) ---------------- */
__global__ void convert_kernel(const float* __restrict__ in, u16* __restrict__ outp, int n4){
  int i = blockIdx.x*blockDim.x + threadIdx.x;
  if (i < n4){
    float4 f = ((const float4*)in)[i];
    u16 o[4] = { f2bf(f.x), f2bf(f.y), f2bf(f.z), f2bf(f.w) };
    ((uint2*)outp)[i] = *(uint2*)o;
  }
}

/* ---- transpose+convert the 8 weight matrices (512x512 fp32) to bf16 N x K ----
   z = w*2 + l ; w: 0=Wq 1=Wk 2=Wv 3=Wo. out[n*512+k] = bf16(in[k*512+n]) */
__global__ void transpose_kernel(const float* __restrict__ Wq, const float* __restrict__ Wk,
                                 const float* __restrict__ Wv, const float* __restrict__ Wo,
                                 u16* __restrict__ WT){
  __shared__ u16 tile[32][33];
  int z = blockIdx.z, wsel = z>>1, l = z&1;
  const float* in = (wsel==0?Wq: wsel==1?Wk: wsel==2?Wv:Wo) + l*262144;
  u16* outp = WT + z*262144;
  int bx = blockIdx.x*32, by = blockIdx.y*32;
  int tx = threadIdx.x, ty = threadIdx.y;           /* block (32,8) */
  for (int r=0;r<32;r+=8) tile[ty+r][tx] = f2bf(in[(by+ty+r)*512 + bx+tx]);
  __syncthreads();
  for (int r=0;r<32;r+=8) outp[(bx+ty+r)*512 + by+tx] = tile[tx][ty+r];
}

/* ---------------- ragged-edge prefix over batches ---------------- */
__global__ void bstart_kernel(const int* __restrict__ edge_len, int* __restrict__ bstart){
  if (threadIdx.x==0 && blockIdx.x==0){
    int s=0;
    for (int b=0;b<N_B;b++){ bstart[b]=s; s+=edge_len[b]; }
    bstart[N_B]=s;
  }
}

/* ---------------- flatten ragged edges + in-degree count ---------------- */
__global__ void scatter_kernel(const int* __restrict__ edge_len, const int* __restrict__ edge_index,
                               const int* __restrict__ relpos_e, const int* __restrict__ deprel_e,
                               const int* __restrict__ deparc_e, const int* __restrict__ bstart,
                               int* __restrict__ src, int* __restrict__ tgt,
                               int* __restrict__ dr, int* __restrict__ da, int* __restrict__ rp,
                               int* __restrict__ deg){
  int idx = blockIdx.x*256 + threadIdx.x;           /* over B*E */
  int b = idx >> 13, e = idx & (N_E-1);
  if (e < edge_len[b]){
    int f = bstart[b] + e;
    int s = edge_index[idx*2+0] + b*N_S;
    int t = edge_index[idx*2+1] + b*N_S;
    src[f]=s; tgt[f]=t;
    dr[f]=deprel_e[idx]; da[f]=deparc_e[idx]; rp[f]=relpos_e[idx];
    atomicAdd(&deg[t], 1);
  }
}

/* ---------------- exclusive scan of degrees (N = 16384 = 1024*16) ---------------- */
__global__ void scan_kernel(const int* __restrict__ deg, int* __restrict__ row_start){
  __shared__ int sums[1024];
  int t = threadIdx.x;
  int base = t*16;
  int local[16]; int s = 0;
  for (int i=0;i<16;i++){ local[i] = s; s += deg[base+i]; }
  sums[t] = s; __syncthreads();
  for (int off=1; off<1024; off<<=1){
    int add = (t >= off) ? sums[t-off] : 0;
    __syncthreads();
    sums[t] += add;
    __syncthreads();
  }
  int prefix = (t>0) ? sums[t-1] : 0;
  for (int i=0;i<16;i++) row_start[base+i] = prefix + local[i];
  if (t==1023) row_start[N_N] = sums[1023];
}

/* ---------------- fill CSR edge lists ---------------- */
__global__ void fill_kernel(const int* __restrict__ edge_len, const int* __restrict__ bstart,
                            const int* __restrict__ tgt, const int* __restrict__ row_start,
                            int* __restrict__ cursor, int* __restrict__ edge_list){
  int idx = blockIdx.x*256 + threadIdx.x;
  int b = idx >> 13, e = idx & (N_E-1);
  if (e < edge_len[b]){
    int f = bstart[b]+e;
    int t = tgt[f];
    int pos = atomicAdd(&cursor[t], 1);
    edge_list[row_start[t]+pos] = f;
  }
}

/* ---- MFMA GEMM: C[M,512] = A[M,512] @ W ; A bf16, Bt is W^T bf16 (N x K row-major) ----
   M=16384, K=512, Nout=512. 128x128x32 tiles, 4 waves (2x2), each 64x64 via 4x4 16x16x32 */
template<bool F32OUT>
__global__ __launch_bounds__(256) void gemm_kernel(const u16* __restrict__ A,
    const u16* __restrict__ B0, const u16* __restrict__ B1, const u16* __restrict__ B2,
    void* __restrict__ C0, void* __restrict__ C1, void* __restrict__ C2){
  const u16* Bt = (blockIdx.z==0) ? B0 : (blockIdx.z==1) ? B1 : B2;
  void* C      = (blockIdx.z==0) ? C0 : (blockIdx.z==1) ? C1 : C2;
  __shared__ __align__(16) u16 As[128][40];   /* +8 pad: 16B-aligned rows */
  __shared__ __align__(16) u16 Bs[128][40];
  int tid  = threadIdx.x;
  int lane = tid & 63, wave = tid >> 6;
  int wm = wave >> 1, wn = wave & 1;
  int quad = lane >> 4, l16 = lane & 15;
  int tileM = blockIdx.y * 128, tileN = blockIdx.x * 128;

  floatx4 acc[4][4];
  for (int i=0;i<4;i++) for (int j=0;j<4;j++) acc[i][j] = (floatx4){0.f,0.f,0.f,0.f};

  for (int k0 = 0; k0 < 512; k0 += 32){
    __syncthreads();
    for (int r = 0; r < 2; r++){
      int c = r*256 + tid;          /* 512 chunks of 16B per tile */
      int row = c >> 2, cc = c & 3;
      *(int4*)&As[row][cc*8] = *(const int4*)&A [(size_t)(tileM+row)*512 + k0 + cc*8];
      *(int4*)&Bs[row][cc*8] = *(const int4*)&Bt[(size_t)(tileN+row)*512 + k0 + cc*8];
    }
    __syncthreads();
    short8 af[4], bfr[4];
    for (int i=0;i<4;i++) af [i] = *(const short8*)&As[wm*64 + i*16 + l16][quad*8];
    for (int j=0;j<4;j++) bfr[j] = *(const short8*)&Bs[wn*64 + j*16 + l16][quad*8];
    for (int i=0;i<4;i++)
      for (int j=0;j<4;j++)
        acc[i][j] = __builtin_amdgcn_mfma_f32_16x16x32_bf16(af[i], bfr[j], acc[i][j], 0,0,0);
  }
  /* C/D layout: col = lane&15, row = quad*4 + reg */
  for (int i=0;i<4;i++)
    for (int j=0;j<4;j++)
      for (int r=0;r<4;r++){
        int row = tileM + wm*64 + i*16 + quad*4 + r;
        int col = tileN + wn*64 + j*16 + l16;
        if (F32OUT) ((float*)C)[(size_t)row*512 + col] = acc[i][j][r];
        else        ((u16*) C)[(size_t)row*512 + col] = f2bf(acc[i][j][r]);
      }
}

/* ---- edge attention v2: one wave per node; lane = (head, dim-chunk) ----
   h = lane>>3 (8 heads), d0 = (lane&7)*8 (8 dims each). One 16B bf16 load per
   lane covers a full 512-elem k/v row per edge. rel shared across heads.
   3-step shfl reduce within 8-lane groups gives all 8 head dots at once.
   Pass 1 stores logits to scratch; pass 2 reloads them (no k reload/redot). */
__global__ __launch_bounds__(256) void edge_attn_kernel(
    const u16* __restrict__ q, const u16* __restrict__ k, const u16* __restrict__ v,
    const int* __restrict__ row_start, const int* __restrict__ edge_list,
    const int* __restrict__ src, const int* __restrict__ dr, const int* __restrict__ da,
    const int* __restrict__ rp,
    const float* __restrict__ deprel_emb, const float* __restrict__ deparc_emb,
    const float* __restrict__ relpos_emb,
    float* __restrict__ logit_ws,
    u16* __restrict__ agg, float* __restrict__ attn_out){
  int t    = (blockIdx.x*blockDim.x + threadIdx.x) >> 6;   /* node */
  int lane = threadIdx.x & 63;
  int h  = lane >> 3;
  int d0 = (lane & 7) * 8;
  int rs = row_start[t], re = row_start[t+1];

  float qv[8];
  {
    uint4 qraw = *(const uint4*)&q[(size_t)t*512 + h*64 + d0];
    const u16* qp = (const u16*)&qraw;
    for (int j=0;j<8;j++) qv[j] = bf2f(qp[j]);
  }

  float m = -1e30f, s = 0.f;
  for (int idx = rs; idx < re; idx++){
    int f  = edge_list[idx];
    int sn = src[f];
    uint4 kraw = *(const uint4*)&k[(size_t)sn*512 + h*64 + d0];
    const u16* kp = (const u16*)&kraw;
    float4 r0 = *(const float4*)&deprel_emb[dr[f]*64 + d0];
    float4 r1 = *(const float4*)&deprel_emb[dr[f]*64 + d0 + 4];
    float4 a0 = *(const float4*)&deparc_emb[da[f]*64 + d0];
    float4 a1 = *(const float4*)&deparc_emb[da[f]*64 + d0 + 4];
    float4 p0 = *(const float4*)&relpos_emb[rp[f]*64 + d0];
    float4 p1 = *(const float4*)&relpos_emb[rp[f]*64 + d0 + 4];
    float rel[8] = { r0.x+a0.x+p0.x, r0.y+a0.y+p0.y, r0.z+a0.z+p0.z, r0.w+a0.w+p0.w,
                     r1.x+a1.x+p1.x, r1.y+a1.y+p1.y, r1.z+a1.z+p1.z, r1.w+a1.w+p1.w };
    float p = 0.f;
    for (int j=0;j<8;j++) p += qv[j] * (bf2f(kp[j]) + rel[j]);
    p += __shfl_xor(p, 1);
    p += __shfl_xor(p, 2);
    p += __shfl_xor(p, 4);
    float logit = p * 0.125f;                 /* 1/sqrt(64) */
    if ((lane & 7) == 0) logit_ws[(size_t)idx*8 + h] = logit;
    float nm = fmaxf(m, logit);
    s = s*__expf(m-nm) + __expf(logit-nm);
    m = nm;
  }
  float invden = 1.f / (s + 1e-9f);

  float acc[8] = {0.f,0.f,0.f,0.f,0.f,0.f,0.f,0.f};
  for (int idx = rs; idx < re; idx++){
    int f  = edge_list[idx];
    int sn = src[f];
    float logit = logit_ws[(size_t)idx*8 + h];
    float alpha = __expf(logit - m) * invden;
    if ((lane & 7) == 0) attn_out[(size_t)f*8 + h] = alpha;
    uint4 vraw = *(const uint4*)&v[(size_t)sn*512 + h*64 + d0];
    const u16* vp = (const u16*)&vraw;
    float4 r0 = *(const float4*)&deprel_emb[dr[f]*64 + d0];
    float4 r1 = *(const float4*)&deprel_emb[dr[f]*64 + d0 + 4];
    float4 a0 = *(const float4*)&deparc_emb[da[f]*64 + d0];
    float4 a1 = *(const float4*)&deparc_emb[da[f]*64 + d0 + 4];
    float4 p0 = *(const float4*)&relpos_emb[rp[f]*64 + d0];
    float4 p1 = *(const float4*)&relpos_emb[rp[f]*64 + d0 + 4];
    float rel[8] = { r0.x+a0.x+p0.x, r0.y+a0.y+p0.y, r0.z+a0.z+p0.z, r0.w+a0.w+p0.w,
                     r1.x+a1.x+p1.x, r1.y+a1.y+p1.y, r1.z+a1.z+p1.z, r1.w+a1.w+p1.w };
    for (int j=0;j<8;j++) acc[j] += alpha * (bf2f(vp[j]) + rel[j]);
  }
  u16 ob[8];
  for (int j=0;j<8;j++) ob[j] = f2bf(acc[j]);
  *(uint4*)&agg[(size_t)t*512 + h*64 + d0] = *(uint4*)ob;
}

/* ---- residual + LayerNorm (+ReLU), wave per row of 512; writes fp32 reps + bf16 hb ---- */
__global__ __launch_bounds__(256) void ln_kernel(const float* __restrict__ out_pre,
    const float* __restrict__ h_in, const float* __restrict__ gamma,
    const float* __restrict__ beta,
    float* __restrict__ outf, u16* __restrict__ hb, int do_relu){
  int wid  = (blockIdx.x*blockDim.x + threadIdx.x) >> 6;   /* row */
  int lane = threadIdx.x & 63;
  const float* xp = out_pre + (size_t)wid*512;
  const float* hp = h_in    + (size_t)wid*512;
  float x[8]; float sum = 0.f;
  for (int i=0;i<8;i++){ int c = lane + i*64; x[i] = xp[c] + hp[c]; sum += x[i]; }
  for (int o=32;o>0;o>>=1) sum += __shfl_xor(sum, o);
  float mu = sum * (1.f/512.f);
  float vs = 0.f;
  for (int i=0;i<8;i++){ float d = x[i]-mu; vs += d*d; }
  for (int o=32;o>0;o>>=1) vs += __shfl_xor(vs, o);
  float inv = rsqrtf(vs*(1.f/512.f) + 1e-5f);
  for (int i=0;i<8;i++){
    int c = lane + i*64;
    float y = (x[i]-mu)*inv*gamma[c] + beta[c];
    if (do_relu) y = fmaxf(y, 0.f);
    outf[(size_t)wid*512 + c] = y;
    hb  [(size_t)wid*512 + c] = f2bf(y);
  }
}

extern "C" void kernel_launch(void* const* d_in, const int* in_sizes, int n_in,
                              void* d_out, int out_size, void* d_ws, size_t ws_size,
                              hipStream_t stream){
  (void)in_sizes; (void)n_in; (void)out_size; (void)ws_size;
  const float* inp      = (const float*)d_in[0];
  const int* edge_len   = (const int*)d_in[2];
  const int* edge_index = (const int*)d_in[3];
  const int* relpos_e   = (const int*)d_in[4];
  const int* deprel_e   = (const int*)d_in[6];
  const int* deparc_e   = (const int*)d_in[7];
  const float* Wq = (const float*)d_in[14];
  const float* Wk = (const float*)d_in[15];
  const float* Wv = (const float*)d_in[16];
  const float* Wo = (const float*)d_in[17];
  const float* deprel_emb = (const float*)d_in[18];
  const float* deparc_emb = (const float*)d_in[19];
  const float* relpos_emb = (const float*)d_in[20];
  const float* ln_scale   = (const float*)d_in[21];
  const float* ln_bias    = (const float*)d_in[22];
  float* outp = (float*)d_out;

  /* ---- carve workspace (~92 MB) ---- */
  char* w = (char*)d_ws;
  auto carve = [&](size_t b)->char*{ char* p = w; w += (b + 255) & ~(size_t)255; return p; };
  u16* WT        = (u16*)carve((size_t)8*262144*2);
  int* bstart    = (int*)carve(32*4);
  int* src       = (int*)carve((size_t)N_BE*4);
  int* tgt       = (int*)carve((size_t)N_BE*4);
  int* dr        = (int*)carve((size_t)N_BE*4);
  int* da        = (int*)carve((size_t)N_BE*4);
  int* rp        = (int*)carve((size_t)N_BE*4);
  int* deg       = (int*)carve((size_t)N_N*4);
  int* cursor    = (int*)carve((size_t)N_N*4);
  int* row_start = (int*)carve((size_t)(N_N+1)*4);
  int* edge_list = (int*)carve((size_t)N_BE*4);
  float* logit_ws= (float*)carve((size_t)N_BE*8*4);
  u16* hb        = (u16*)carve((size_t)N_N*512*2);
  u16* qb        = (u16*)carve((size_t)N_N*512*2);   /* qb+kb also alias out_pre (fp32) */
  u16* kb        = (u16*)carve((size_t)N_N*512*2);
  u16* vb        = (u16*)carve((size_t)N_N*512*2);
  u16* aggb      = (u16*)carve((size_t)N_N*512*2);
  float* out_pre = (float*)qb;   /* 32MB alias over qb+kb, dead by the time it's written */

  /* ---- per-call setup ---- */
  transpose_kernel<<<dim3(16,16,8), dim3(32,8), 0, stream>>>(Wq,Wk,Wv,Wo, WT);
  convert_kernel<<<dim3(8192), dim3(256), 0, stream>>>(inp, hb, N_N*512/4);
  zero_kernel<<<dim3(64),   dim3(256), 0, stream>>>((u32*)deg,    N_N);
  zero_kernel<<<dim3(64),   dim3(256), 0, stream>>>((u32*)cursor, N_N);
  u32* attn_all = (u32*)(outp + (size_t)N_L*N_N*512);
  zero_kernel<<<dim3(8192), dim3(256), 0, stream>>>(attn_all, N_L*N_BE*N_H);
  bstart_kernel<<<dim3(1), dim3(1), 0, stream>>>(edge_len, bstart);
  scatter_kernel<<<dim3(N_BE/256), dim3(256), 0, stream>>>(edge_len, edge_index,
      relpos_e, deprel_e, deparc_e, bstart, src, tgt, dr, da, rp, deg);
  scan_kernel<<<dim3(1), dim3(1024), 0, stream>>>(deg, row_start);
  fill_kernel<<<dim3(N_BE/256), dim3(256), 0, stream>>>(edge_len, bstart, tgt,
      row_start, cursor, edge_list);

  /* ---- layers ---- */
  for (int l=0; l<N_L; l++){
    float* reps_out = outp + (size_t)l*N_N*512;
    float* attn_out = outp + (size_t)N_L*N_N*512 + (size_t)l*N_BE*N_H;
    const u16* WqT = WT + (0*2 + l)*262144;
    const u16* WkT = WT + (1*2 + l)*262144;
    const u16* WvT = WT + (2*2 + l)*262144;
    const u16* WoT = WT + (3*2 + l)*262144;

    gemm_kernel<false><<<dim3(4,128,3), dim3(256), 0, stream>>>(hb,
        WqT, WkT, WvT, (void*)qb, (void*)kb, (void*)vb);

    edge_attn_kernel<<<dim3(N_N/4), dim3(256), 0, stream>>>(qb, kb, vb,
        row_start, edge_list, src, dr, da, rp,
        deprel_emb + l*50*64, deparc_emb + l*3*64, relpos_emb + l*21*64,
        logit_ws, aggb, attn_out);

    gemm_kernel<true><<<dim3(4,128,1), dim3(256), 0, stream>>>(aggb,
        WoT, WoT, WoT, (void*)out_pre, (void*)out_pre, (void*)out_pre);

    ln_kernel<<<dim3(N_N/4), dim3(256), 0, stream>>>(out_pre,
        (l==0) ? inp : outp,            /* residual: inp or reps[0] */
        ln_scale + l*512, ln_bias + l*512, reps_out, hb, (l==0)?1:0);
  }
}

// Round 6
// 427.937 us; speedup vs baseline: 1.8425x; 1.0869x over previous
//
#include <hip/hip_runtime.h>

typedef unsigned short u16;
typedef unsigned int   u32;
typedef __attribute__((ext_vector_type(8))) short short8;
typedef __attribute__((ext_vector_type(4))) float floatx4;

#define N_B  16
#define N_S  1024
#define N_E  8192
#define N_D  512
#define N_H  8
#define N_DK 64
#define N_L  2
#define N_N  (N_B*N_S)   /* 16384 */
#define N_BE (N_B*N_E)   /* 131072 */

__device__ __forceinline__ float bf2f(u16 u){ return __uint_as_float(((u32)u)<<16); }
__device__ __forceinline__ u16 f2bf(float f){
  u32 i = __float_as_uint(f);
  return (u16)((i + 0x7fffu + ((i>>16)&1u)) >> 16);
}

/* ---------------- generic zero ---------------- */
__global__ void zero_kernel(u32* __restrict__ p, int n){
  int i = blockIdx.x*blockDim.x + threadIdx.x;
  if (i < n) p[i] = 0;
}

/* ---------------- fp32 -> bf16 convert (4 elems/thread) ---------------- */
__global__ void convert_kernel(const float* __restrict__ in, u16* __restrict__ outp, int n4){
  int i = blockIdx.x*blockDim.x + threadIdx.x;
  if (i < n4){
    float4 f = ((const float4*)in)[i];
    u16 o[4] = { f2bf(f.x), f2bf(f.y), f2bf(f.z), f2bf(f.w) };
    ((uint2*)outp)[i] = *(uint2*)o;
  }
}

/* ---- transpose+convert the 8 weight matrices (512x512 fp32) to bf16 N x K ---- */
__global__ void transpose_kernel(const float* __restrict__ Wq, const float* __restrict__ Wk,
                                 const float* __restrict__ Wv, const float* __restrict__ Wo,
                                 u16* __restrict__ WT){
  __shared__ u16 tile[32][33];
  int z = blockIdx.z, wsel = z>>1, l = z&1;
  const float* in = (wsel==0?Wq: wsel==1?Wk: wsel==2?Wv:Wo) + l*262144;
  u16* outp = WT + z*262144;
  int bx = blockIdx.x*32, by = blockIdx.y*32;
  int tx = threadIdx.x, ty = threadIdx.y;           /* block (32,8) */
  for (int r=0;r<32;r+=8) tile[ty+r][tx] = f2bf(in[(by+ty+r)*512 + bx+tx]);
  __syncthreads();
  for (int r=0;r<32;r+=8) outp[(bx+ty+r)*512 + by+tx] = tile[tx][ty+r];
}

/* ---------------- ragged-edge prefix over batches ---------------- */
__global__ void bstart_kernel(const int* __restrict__ edge_len, int* __restrict__ bstart){
  if (threadIdx.x==0 && blockIdx.x==0){
    int s=0;
    for (int b=0;b<N_B;b++){ bstart[b]=s; s+=edge_len[b]; }
    bstart[N_B]=s;
  }
}

/* ---------------- in-degree count ---------------- */
__global__ void count_kernel(const int* __restrict__ edge_len, const int* __restrict__ edge_index,
                             int* __restrict__ deg){
  int idx = blockIdx.x*256 + threadIdx.x;           /* over B*E */
  int b = idx >> 13, e = idx & (N_E-1);
  if (e < edge_len[b]){
    int t = edge_index[idx*2+1] + b*N_S;
    atomicAdd(&deg[t], 1);
  }
}

/* ---------------- exclusive scan of degrees (N = 16384 = 1024*16) ---------------- */
__global__ void scan_kernel(const int* __restrict__ deg, int* __restrict__ row_start){
  __shared__ int sums[1024];
  int t = threadIdx.x;
  int base = t*16;
  int local[16]; int s = 0;
  for (int i=0;i<16;i++){ local[i] = s; s += deg[base+i]; }
  sums[t] = s; __syncthreads();
  for (int off=1; off<1024; off<<=1){
    int add = (t >= off) ? sums[t-off] : 0;
    __syncthreads();
    sums[t] += add;
    __syncthreads();
  }
  int prefix = (t>0) ? sums[t-1] : 0;
  for (int i=0;i<16;i++) row_start[base+i] = prefix + local[i];
  if (t==1023) row_start[N_N] = sums[1023];
}

/* ---- fill CSR: reorder src / packed-meta / flat-edge-id into CSR slot order ---- */
__global__ void fill_kernel(const int* __restrict__ edge_len, const int* __restrict__ edge_index,
                            const int* __restrict__ relpos_e, const int* __restrict__ deprel_e,
                            const int* __restrict__ deparc_e, const int* __restrict__ bstart,
                            const int* __restrict__ row_start, int* __restrict__ cursor,
                            int* __restrict__ csr_src, int* __restrict__ csr_meta,
                            int* __restrict__ csr_f){
  int idx = blockIdx.x*256 + threadIdx.x;
  int b = idx >> 13, e = idx & (N_E-1);
  if (e < edge_len[b]){
    int f = bstart[b]+e;
    int s = edge_index[idx*2+0] + b*N_S;
    int t = edge_index[idx*2+1] + b*N_S;
    int pos = atomicAdd(&cursor[t], 1);
    int slot = row_start[t] + pos;
    csr_src[slot]  = s;
    csr_meta[slot] = deprel_e[idx] | (deparc_e[idx]<<6) | (relpos_e[idx]<<8);
    csr_f[slot]    = f;
  }
}

/* ---- MFMA GEMM: C[M,512] = A[M,512] @ W ; A bf16, Bt is W^T bf16 (N x K row-major) ---- */
template<bool F32OUT>
__global__ __launch_bounds__(256) void gemm_kernel(const u16* __restrict__ A,
    const u16* __restrict__ B0, const u16* __restrict__ B1, const u16* __restrict__ B2,
    void* __restrict__ C0, void* __restrict__ C1, void* __restrict__ C2){
  const u16* Bt = (blockIdx.z==0) ? B0 : (blockIdx.z==1) ? B1 : B2;
  void* C      = (blockIdx.z==0) ? C0 : (blockIdx.z==1) ? C1 : C2;
  __shared__ __align__(16) u16 As[128][40];   /* +8 pad: 16B-aligned rows */
  __shared__ __align__(16) u16 Bs[128][40];
  int tid  = threadIdx.x;
  int lane = tid & 63, wave = tid >> 6;
  int wm = wave >> 1, wn = wave & 1;
  int quad = lane >> 4, l16 = lane & 15;
  int tileM = blockIdx.y * 128, tileN = blockIdx.x * 128;

  floatx4 acc[4][4];
  for (int i=0;i<4;i++) for (int j=0;j<4;j++) acc[i][j] = (floatx4){0.f,0.f,0.f,0.f};

  for (int k0 = 0; k0 < 512; k0 += 32){
    __syncthreads();
    for (int r = 0; r < 2; r++){
      int c = r*256 + tid;          /* 512 chunks of 16B per tile */
      int row = c >> 2, cc = c & 3;
      *(int4*)&As[row][cc*8] = *(const int4*)&A [(size_t)(tileM+row)*512 + k0 + cc*8];
      *(int4*)&Bs[row][cc*8] = *(const int4*)&Bt[(size_t)(tileN+row)*512 + k0 + cc*8];
    }
    __syncthreads();
    short8 af[4], bfr[4];
    for (int i=0;i<4;i++) af [i] = *(const short8*)&As[wm*64 + i*16 + l16][quad*8];
    for (int j=0;j<4;j++) bfr[j] = *(const short8*)&Bs[wn*64 + j*16 + l16][quad*8];
    for (int i=0;i<4;i++)
      for (int j=0;j<4;j++)
        acc[i][j] = __builtin_amdgcn_mfma_f32_16x16x32_bf16(af[i], bfr[j], acc[i][j], 0,0,0);
  }
  /* C/D layout: col = lane&15, row = quad*4 + reg */
  for (int i=0;i<4;i++)
    for (int j=0;j<4;j++)
      for (int r=0;r<4;r++){
        int row = tileM + wm*64 + i*16 + quad*4 + r;
        int col = tileN + wn*64 + j*16 + l16;
        if (F32OUT) ((float*)C)[(size_t)row*512 + col] = acc[i][j][r];
        else        ((u16*) C)[(size_t)row*512 + col] = f2bf(acc[i][j][r]);
      }
}

/* ---- edge attention v3: single pass, no max (logits are O(1), exp fp32-safe),
   one wave per node, lane = (head, dim-chunk); XCD-swizzled block mapping so
   each XCD's L2 holds ~2 batches of k/v (~4MB). e-values spill to 4MB scratch,
   mini-loop rescales them into attn_out. ---- */
__global__ __launch_bounds__(256) void edge_attn_kernel(
    const u16* __restrict__ q, const u16* __restrict__ k, const u16* __restrict__ v,
    const int* __restrict__ row_start,
    const int* __restrict__ csr_src, const int* __restrict__ csr_meta,
    const int* __restrict__ csr_f,
    const float* __restrict__ deprel_emb, const float* __restrict__ deparc_emb,
    const float* __restrict__ relpos_emb,
    float* __restrict__ e_ws,
    u16* __restrict__ agg, float* __restrict__ attn_out){
  int bid = blockIdx.x;
  int lb  = (bid & 7) * (gridDim.x >> 3) + (bid >> 3);   /* XCD-contiguous remap */
  int t    = lb*4 + (threadIdx.x >> 6);                  /* node */
  int lane = threadIdx.x & 63;
  int h  = lane >> 3;
  int d0 = (lane & 7) * 8;
  int rs = row_start[t], re = row_start[t+1];

  float qv[8];
  {
    uint4 qraw = *(const uint4*)&q[(size_t)t*512 + h*64 + d0];
    const u16* qp = (const u16*)&qraw;
    for (int j=0;j<8;j++) qv[j] = bf2f(qp[j]);
  }

  float s = 0.f;
  float acc[8] = {0.f,0.f,0.f,0.f,0.f,0.f,0.f,0.f};
  for (int idx = rs; idx < re; idx++){
    int sn   = csr_src[idx];
    int meta = csr_meta[idx];
    int dr = meta & 63, da = (meta>>6) & 3, rp = meta >> 8;
    uint4 kraw = *(const uint4*)&k[(size_t)sn*512 + h*64 + d0];
    uint4 vraw = *(const uint4*)&v[(size_t)sn*512 + h*64 + d0];
    const u16* kp = (const u16*)&kraw;
    const u16* vp = (const u16*)&vraw;
    float4 r0 = *(const float4*)&deprel_emb[dr*64 + d0];
    float4 r1 = *(const float4*)&deprel_emb[dr*64 + d0 + 4];
    float4 a0 = *(const float4*)&deparc_emb[da*64 + d0];
    float4 a1 = *(const float4*)&deparc_emb[da*64 + d0 + 4];
    float4 p0 = *(const float4*)&relpos_emb[rp*64 + d0];
    float4 p1 = *(const float4*)&relpos_emb[rp*64 + d0 + 4];
    float rel[8] = { r0.x+a0.x+p0.x, r0.y+a0.y+p0.y, r0.z+a0.z+p0.z, r0.w+a0.w+p0.w,
                     r1.x+a1.x+p1.x, r1.y+a1.y+p1.y, r1.z+a1.z+p1.z, r1.w+a1.w+p1.w };
    float p = 0.f;
    for (int j=0;j<8;j++) p += qv[j] * (bf2f(kp[j]) + rel[j]);
    p += __shfl_xor(p, 1);
    p += __shfl_xor(p, 2);
    p += __shfl_xor(p, 4);
    float e = __expf(p * 0.125f);             /* 1/sqrt(64); logits O(1) so no max needed */
    if ((lane & 7) == 0) e_ws[(size_t)idx*8 + h] = e;
    s += e;
    for (int j=0;j<8;j++) acc[j] += e * (bf2f(vp[j]) + rel[j]);
  }
  float invden = 1.f / (s + 1e-9f);

  /* alpha write-back: only scratch + attn_out touched (L2-hot) */
  if ((lane & 7) == 0){
    for (int idx = rs; idx < re; idx++){
      float e = e_ws[(size_t)idx*8 + h];
      attn_out[(size_t)csr_f[idx]*8 + h] = e * invden;
    }
  }

  u16 ob[8];
  for (int j=0;j<8;j++) ob[j] = f2bf(acc[j] * invden);
  *(uint4*)&agg[(size_t)t*512 + h*64 + d0] = *(uint4*)ob;
}

/* ---- residual + LayerNorm (+ReLU), wave per row of 512; writes fp32 reps + bf16 hb ---- */
__global__ __launch_bounds__(256) void ln_kernel(const float* __restrict__ out_pre,
    const float* __restrict__ h_in, const float* __restrict__ gamma,
    const float* __restrict__ beta,
    float* __restrict__ outf, u16* __restrict__ hb, int do_relu){
  int wid  = (blockIdx.x*blockDim.x + threadIdx.x) >> 6;   /* row */
  int lane = threadIdx.x & 63;
  const float* xp = out_pre + (size_t)wid*512;
  const float* hp = h_in    + (size_t)wid*512;
  float x[8]; float sum = 0.f;
  for (int i=0;i<8;i++){ int c = lane + i*64; x[i] = xp[c] + hp[c]; sum += x[i]; }
  for (int o=32;o>0;o>>=1) sum += __shfl_xor(sum, o);
  float mu = sum * (1.f/512.f);
  float vs = 0.f;
  for (int i=0;i<8;i++){ float d = x[i]-mu; vs += d*d; }
  for (int o=32;o>0;o>>=1) vs += __shfl_xor(vs, o);
  float inv = rsqrtf(vs*(1.f/512.f) + 1e-5f);
  for (int i=0;i<8;i++){
    int c = lane + i*64;
    float y = (x[i]-mu)*inv*gamma[c] + beta[c];
    if (do_relu) y = fmaxf(y, 0.f);
    outf[(size_t)wid*512 + c] = y;
    hb  [(size_t)wid*512 + c] = f2bf(y);
  }
}

extern "C" void kernel_launch(void* const* d_in, const int* in_sizes, int n_in,
                              void* d_out, int out_size, void* d_ws, size_t ws_size,
                              hipStream_t stream){
  (void)in_sizes; (void)n_in; (void)out_size; (void)ws_size;
  const float* inp      = (const float*)d_in[0];
  const int* edge_len   = (const int*)d_in[2];
  const int* edge_index = (const int*)d_in[3];
  const int* relpos_e   = (const int*)d_in[4];
  const int* deprel_e   = (const int*)d_in[6];
  const int* deparc_e   = (const int*)d_in[7];
  const float* Wq = (const float*)d_in[14];
  const float* Wk = (const float*)d_in[15];
  const float* Wv = (const float*)d_in[16];
  const float* Wo = (const float*)d_in[17];
  const float* deprel_emb = (const float*)d_in[18];
  const float* deparc_emb = (const float*)d_in[19];
  const float* relpos_emb = (const float*)d_in[20];
  const float* ln_scale   = (const float*)d_in[21];
  const float* ln_bias    = (const float*)d_in[22];
  float* outp = (float*)d_out;

  /* ---- carve workspace (~91 MB) ---- */
  char* w = (char*)d_ws;
  auto carve = [&](size_t b)->char*{ char* p = w; w += (b + 255) & ~(size_t)255; return p; };
  u16* WT        = (u16*)carve((size_t)8*262144*2);
  int* bstart    = (int*)carve(32*4);
  int* deg       = (int*)carve((size_t)N_N*4);
  int* cursor    = (int*)carve((size_t)N_N*4);
  int* row_start = (int*)carve((size_t)(N_N+1)*4);
  int* csr_src   = (int*)carve((size_t)N_BE*4);
  int* csr_meta  = (int*)carve((size_t)N_BE*4);
  int* csr_f     = (int*)carve((size_t)N_BE*4);
  float* e_ws    = (float*)carve((size_t)N_BE*8*4);
  u16* hb        = (u16*)carve((size_t)N_N*512*2);
  u16* qb        = (u16*)carve((size_t)N_N*512*2);   /* qb+kb alias out_pre (fp32) */
  u16* kb        = (u16*)carve((size_t)N_N*512*2);
  u16* vb        = (u16*)carve((size_t)N_N*512*2);
  u16* aggb      = (u16*)carve((size_t)N_N*512*2);
  float* out_pre = (float*)qb;   /* 32MB alias over qb+kb, dead by the time it's written */

  /* ---- per-call setup ---- */
  transpose_kernel<<<dim3(16,16,8), dim3(32,8), 0, stream>>>(Wq,Wk,Wv,Wo, WT);
  convert_kernel<<<dim3(8192), dim3(256), 0, stream>>>(inp, hb, N_N*512/4);
  zero_kernel<<<dim3(64),   dim3(256), 0, stream>>>((u32*)deg,    N_N);
  zero_kernel<<<dim3(64),   dim3(256), 0, stream>>>((u32*)cursor, N_N);
  u32* attn_all = (u32*)(outp + (size_t)N_L*N_N*512);
  zero_kernel<<<dim3(8192), dim3(256), 0, stream>>>(attn_all, N_L*N_BE*N_H);
  bstart_kernel<<<dim3(1), dim3(1), 0, stream>>>(edge_len, bstart);
  count_kernel<<<dim3(N_BE/256), dim3(256), 0, stream>>>(edge_len, edge_index, deg);
  scan_kernel<<<dim3(1), dim3(1024), 0, stream>>>(deg, row_start);
  fill_kernel<<<dim3(N_BE/256), dim3(256), 0, stream>>>(edge_len, edge_index,
      relpos_e, deprel_e, deparc_e, bstart, row_start, cursor,
      csr_src, csr_meta, csr_f);

  /* ---- layers ---- */
  for (int l=0; l<N_L; l++){
    float* reps_out = outp + (size_t)l*N_N*512;
    float* attn_out = outp + (size_t)N_L*N_N*512 + (size_t)l*N_BE*N_H;
    const u16* WqT = WT + (0*2 + l)*262144;
    const u16* WkT = WT + (1*2 + l)*262144;
    const u16* WvT = WT + (2*2 + l)*262144;
    const u16* WoT = WT + (3*2 + l)*262144;

    gemm_kernel<false><<<dim3(4,128,3), dim3(256), 0, stream>>>(hb,
        WqT, WkT, WvT, (void*)qb, (void*)kb, (void*)vb);

    edge_attn_kernel<<<dim3(N_N/4), dim3(256), 0, stream>>>(qb, kb, vb,
        row_start, csr_src, csr_meta, csr_f,
        deprel_emb + l*50*64, deparc_emb + l*3*64, relpos_emb + l*21*64,
        e_ws, aggb, attn_out);

    gemm_kernel<true><<<dim3(4,128,1), dim3(256), 0, stream>>>(aggb,
        WoT, WoT, WoT, (void*)out_pre, (void*)out_pre, (void*)out_pre);

    ln_kernel<<<dim3(N_N/4), dim3(256), 0, stream>>>(out_pre,
        (l==0) ? inp : outp,            /* residual: inp or reps[0] */
        ln_scale + l*512, ln_bias + l*512, reps_out, hb, (l==0)?1:0);
  }
}

// Round 7
// 410.710 us; speedup vs baseline: 1.9198x; 1.0419x over previous
//
#include <hip/hip_runtime.h>

typedef unsigned short u16;
typedef unsigned int   u32;
typedef __attribute__((ext_vector_type(8))) short short8;
typedef __attribute__((ext_vector_type(4))) float floatx4;

#define N_B  16
#define N_S  1024
#define N_E  8192
#define N_D  512
#define N_H  8
#define N_DK 64
#define N_L  2
#define N_N  (N_B*N_S)   /* 16384 */
#define N_BE (N_B*N_E)   /* 131072 */
#define N_COMBO 3150     /* 50*3*21 rel-combos */

__device__ __forceinline__ float bf2f(u16 u){ return __uint_as_float(((u32)u)<<16); }
__device__ __forceinline__ u16 f2bf(float f){
  u32 i = __float_as_uint(f);
  return (u16)((i + 0x7fffu + ((i>>16)&1u)) >> 16);
}

/* ---------------- generic zero ---------------- */
__global__ void zero_kernel(u32* __restrict__ p, int n){
  int i = blockIdx.x*blockDim.x + threadIdx.x;
  if (i < n) p[i] = 0;
}

/* ---------------- fp32 -> bf16 convert (4 elems/thread) ---------------- */
__global__ void convert_kernel(const float* __restrict__ in, u16* __restrict__ outp, int n4){
  int i = blockIdx.x*blockDim.x + threadIdx.x;
  if (i < n4){
    float4 f = ((const float4*)in)[i];
    u16 o[4] = { f2bf(f.x), f2bf(f.y), f2bf(f.z), f2bf(f.w) };
    ((uint2*)outp)[i] = *(uint2*)o;
  }
}

/* ---- transpose+convert the 8 weight matrices (512x512 fp32) to bf16 N x K ---- */
__global__ void transpose_kernel(const float* __restrict__ Wq, const float* __restrict__ Wk,
                                 const float* __restrict__ Wv, const float* __restrict__ Wo,
                                 u16* __restrict__ WT){
  __shared__ u16 tile[32][33];
  int z = blockIdx.z, wsel = z>>1, l = z&1;
  const float* in = (wsel==0?Wq: wsel==1?Wk: wsel==2?Wv:Wo) + l*262144;
  u16* outp = WT + z*262144;
  int bx = blockIdx.x*32, by = blockIdx.y*32;
  int tx = threadIdx.x, ty = threadIdx.y;           /* block (32,8) */
  for (int r=0;r<32;r+=8) tile[ty+r][tx] = f2bf(in[(by+ty+r)*512 + bx+tx]);
  __syncthreads();
  for (int r=0;r<32;r+=8) outp[(bx+ty+r)*512 + by+tx] = tile[tx][ty+r];
}

/* ---------------- ragged-edge prefix over batches ---------------- */
__global__ void bstart_kernel(const int* __restrict__ edge_len, int* __restrict__ bstart){
  if (threadIdx.x==0 && blockIdx.x==0){
    int s=0;
    for (int b=0;b<N_B;b++){ bstart[b]=s; s+=edge_len[b]; }
    bstart[N_B]=s;
  }
}

/* ---------------- in-degree count ---------------- */
__global__ void count_kernel(const int* __restrict__ edge_len, const int* __restrict__ edge_index,
                             int* __restrict__ deg){
  int idx = blockIdx.x*256 + threadIdx.x;           /* over B*E */
  int b = idx >> 13, e = idx & (N_E-1);
  if (e < edge_len[b]){
    int t = edge_index[idx*2+1] + b*N_S;
    atomicAdd(&deg[t], 1);
  }
}

/* ---------------- exclusive scan of degrees (N = 16384 = 1024*16) ---------------- */
__global__ void scan_kernel(const int* __restrict__ deg, int* __restrict__ row_start){
  __shared__ int sums[1024];
  int t = threadIdx.x;
  int base = t*16;
  int local[16]; int s = 0;
  for (int i=0;i<16;i++){ local[i] = s; s += deg[base+i]; }
  sums[t] = s; __syncthreads();
  for (int off=1; off<1024; off<<=1){
    int add = (t >= off) ? sums[t-off] : 0;
    __syncthreads();
    sums[t] += add;
    __syncthreads();
  }
  int prefix = (t>0) ? sums[t-1] : 0;
  for (int i=0;i<16;i++) row_start[base+i] = prefix + local[i];
  if (t==1023) row_start[N_N] = sums[1023];
}

/* ---- fill CSR: src / combo-meta / flat-edge-id into CSR order; also f->tgt map ---- */
__global__ void fill_kernel(const int* __restrict__ edge_len, const int* __restrict__ edge_index,
                            const int* __restrict__ relpos_e, const int* __restrict__ deprel_e,
                            const int* __restrict__ deparc_e, const int* __restrict__ bstart,
                            const int* __restrict__ row_start, int* __restrict__ cursor,
                            int* __restrict__ csr_src, int* __restrict__ csr_meta,
                            int* __restrict__ csr_f, int* __restrict__ tgt_f){
  int idx = blockIdx.x*256 + threadIdx.x;
  int b = idx >> 13, e = idx & (N_E-1);
  if (e < edge_len[b]){
    int f = bstart[b]+e;
    int s = edge_index[idx*2+0] + b*N_S;
    int t = edge_index[idx*2+1] + b*N_S;
    int pos = atomicAdd(&cursor[t], 1);
    int slot = row_start[t] + pos;
    csr_src[slot]  = s;
    csr_meta[slot] = deprel_e[idx] + 50*deparc_e[idx] + 150*relpos_e[idx];
    csr_f[slot]    = f;
    tgt_f[f]       = t;
  }
}

/* ---- per-layer rel table: rel_table[combo*64+d] = bf16(dre+dae+rpe) ---- */
__global__ void rel_kernel(const float* __restrict__ dre, const float* __restrict__ dae,
                           const float* __restrict__ rpe, u16* __restrict__ rel_table){
  int i = blockIdx.x*256 + threadIdx.x;     /* over 3150*64 */
  if (i < N_COMBO*64){
    int combo = i >> 6, d = i & 63;
    int dr = combo % 50, da = (combo/50) % 3, rp = combo/150;
    rel_table[i] = f2bf(dre[dr*64+d] + dae[da*64+d] + rpe[rp*64+d]);
  }
}

/* ---- MFMA GEMM: C[M,512] = A[M,512] @ W ; A bf16, Bt is W^T bf16 (N x K row-major) ---- */
template<bool F32OUT>
__global__ __launch_bounds__(256) void gemm_kernel(const u16* __restrict__ A,
    const u16* __restrict__ B0, const u16* __restrict__ B1, const u16* __restrict__ B2,
    void* __restrict__ C0, void* __restrict__ C1, void* __restrict__ C2){
  const u16* Bt = (blockIdx.z==0) ? B0 : (blockIdx.z==1) ? B1 : B2;
  void* C      = (blockIdx.z==0) ? C0 : (blockIdx.z==1) ? C1 : C2;
  __shared__ __align__(16) u16 As[128][40];   /* +8 pad: 16B-aligned rows */
  __shared__ __align__(16) u16 Bs[128][40];
  int tid  = threadIdx.x;
  int lane = tid & 63, wave = tid >> 6;
  int wm = wave >> 1, wn = wave & 1;
  int quad = lane >> 4, l16 = lane & 15;
  int tileM = blockIdx.y * 128, tileN = blockIdx.x * 128;

  floatx4 acc[4][4];
  for (int i=0;i<4;i++) for (int j=0;j<4;j++) acc[i][j] = (floatx4){0.f,0.f,0.f,0.f};

  for (int k0 = 0; k0 < 512; k0 += 32){
    __syncthreads();
    for (int r = 0; r < 2; r++){
      int c = r*256 + tid;          /* 512 chunks of 16B per tile */
      int row = c >> 2, cc = c & 3;
      *(int4*)&As[row][cc*8] = *(const int4*)&A [(size_t)(tileM+row)*512 + k0 + cc*8];
      *(int4*)&Bs[row][cc*8] = *(const int4*)&Bt[(size_t)(tileN+row)*512 + k0 + cc*8];
    }
    __syncthreads();
    short8 af[4], bfr[4];
    for (int i=0;i<4;i++) af [i] = *(const short8*)&As[wm*64 + i*16 + l16][quad*8];
    for (int j=0;j<4;j++) bfr[j] = *(const short8*)&Bs[wn*64 + j*16 + l16][quad*8];
    for (int i=0;i<4;i++)
      for (int j=0;j<4;j++)
        acc[i][j] = __builtin_amdgcn_mfma_f32_16x16x32_bf16(af[i], bfr[j], acc[i][j], 0,0,0);
  }
  /* C/D layout: col = lane&15, row = quad*4 + reg */
  for (int i=0;i<4;i++)
    for (int j=0;j<4;j++)
      for (int r=0;r<4;r++){
        int row = tileM + wm*64 + i*16 + quad*4 + r;
        int col = tileN + wn*64 + j*16 + l16;
        if (F32OUT) ((float*)C)[(size_t)row*512 + col] = acc[i][j][r];
        else        ((u16*) C)[(size_t)row*512 + col] = f2bf(acc[i][j][r]);
      }
}

/* ---- edge attention v4: single pass, unroll-2, rel_table, no epilogue loop.
   One wave per node, lane = (head h=lane>>3, dims d0=(lane&7)*8). Writes raw e
   to attn_out and denominator s to den_ws; rescale_kernel normalizes. ---- */
__global__ __launch_bounds__(256) void edge_attn_kernel(
    const u16* __restrict__ q, const u16* __restrict__ k, const u16* __restrict__ v,
    const int* __restrict__ row_start,
    const int* __restrict__ csr_src, const int* __restrict__ csr_meta,
    const int* __restrict__ csr_f, const u16* __restrict__ rel_table,
    float* __restrict__ den_ws,
    u16* __restrict__ agg, float* __restrict__ attn_out){
  int bid = blockIdx.x;
  int lb  = (bid & 7) * (gridDim.x >> 3) + (bid >> 3);   /* XCD-contiguous remap */
  int t    = lb*4 + (threadIdx.x >> 6);                  /* node */
  int lane = threadIdx.x & 63;
  int h  = lane >> 3;
  int d0 = (lane & 7) * 8;
  int rs = row_start[t], re = row_start[t+1];

  float qv[8];
  {
    uint4 qraw = *(const uint4*)&q[(size_t)t*512 + h*64 + d0];
    const u16* qp = (const u16*)&qraw;
    for (int j=0;j<8;j++) qv[j] = bf2f(qp[j]);
  }

  float s = 0.f;
  float acc[8] = {0.f,0.f,0.f,0.f,0.f,0.f,0.f,0.f};
  int idx = rs;
  for (; idx + 1 < re; idx += 2){
    int sn0 = csr_src[idx],   mi0 = csr_meta[idx],   f0 = csr_f[idx];
    int sn1 = csr_src[idx+1], mi1 = csr_meta[idx+1], f1 = csr_f[idx+1];
    uint4 k0 = *(const uint4*)&k[(size_t)sn0*512 + h*64 + d0];
    uint4 v0 = *(const uint4*)&v[(size_t)sn0*512 + h*64 + d0];
    uint4 r0 = *(const uint4*)&rel_table[mi0*64 + d0];
    uint4 k1 = *(const uint4*)&k[(size_t)sn1*512 + h*64 + d0];
    uint4 v1 = *(const uint4*)&v[(size_t)sn1*512 + h*64 + d0];
    uint4 r1 = *(const uint4*)&rel_table[mi1*64 + d0];
    const u16 *kp0=(const u16*)&k0, *vp0=(const u16*)&v0, *rp0=(const u16*)&r0;
    const u16 *kp1=(const u16*)&k1, *vp1=(const u16*)&v1, *rp1=(const u16*)&r1;
    float rel0[8], rel1[8];
    for (int j=0;j<8;j++){ rel0[j]=bf2f(rp0[j]); rel1[j]=bf2f(rp1[j]); }
    float p0 = 0.f, p1 = 0.f;
    for (int j=0;j<8;j++){ p0 += qv[j]*(bf2f(kp0[j])+rel0[j]);
                           p1 += qv[j]*(bf2f(kp1[j])+rel1[j]); }
    p0 += __shfl_xor(p0,1); p1 += __shfl_xor(p1,1);
    p0 += __shfl_xor(p0,2); p1 += __shfl_xor(p1,2);
    p0 += __shfl_xor(p0,4); p1 += __shfl_xor(p1,4);
    float e0 = __expf(p0*0.125f), e1 = __expf(p1*0.125f);
    if ((lane & 7) == 0){
      attn_out[(size_t)f0*8 + h] = e0;
      attn_out[(size_t)f1*8 + h] = e1;
    }
    s += e0 + e1;
    for (int j=0;j<8;j++) acc[j] += e0*(bf2f(vp0[j])+rel0[j]) + e1*(bf2f(vp1[j])+rel1[j]);
  }
  if (idx < re){
    int sn0 = csr_src[idx], mi0 = csr_meta[idx], f0 = csr_f[idx];
    uint4 k0 = *(const uint4*)&k[(size_t)sn0*512 + h*64 + d0];
    uint4 v0 = *(const uint4*)&v[(size_t)sn0*512 + h*64 + d0];
    uint4 r0 = *(const uint4*)&rel_table[mi0*64 + d0];
    const u16 *kp0=(const u16*)&k0, *vp0=(const u16*)&v0, *rp0=(const u16*)&r0;
    float p0 = 0.f;
    for (int j=0;j<8;j++) p0 += qv[j]*(bf2f(kp0[j])+bf2f(rp0[j]));
    p0 += __shfl_xor(p0,1);
    p0 += __shfl_xor(p0,2);
    p0 += __shfl_xor(p0,4);
    float e0 = __expf(p0*0.125f);
    if ((lane & 7) == 0) attn_out[(size_t)f0*8 + h] = e0;
    s += e0;
    for (int j=0;j<8;j++) acc[j] += e0*(bf2f(vp0[j])+bf2f(rp0[j]));
  }
  float invden = 1.f / (s + 1e-9f);
  if ((lane & 7) == 0) den_ws[t*8 + h] = s;

  u16 ob[8];
  for (int j=0;j<8;j++) ob[j] = f2bf(acc[j] * invden);
  *(uint4*)&agg[(size_t)t*512 + h*64 + d0] = *(uint4*)ob;
}

/* ---- rescale: alpha = e / (den[tgt]+1e-9), float4 per thread over BE*8 floats ---- */
__global__ void rescale_kernel(float* __restrict__ attn, const int* __restrict__ tgt_f,
                               const float* __restrict__ den_ws){
  int i = blockIdx.x*256 + threadIdx.x;     /* over N_BE*2 float4s */
  int f = i >> 1;
  int t = tgt_f[f];
  float4 e = ((float4*)attn)[i];
  float4 d = *(const float4*)&den_ws[t*8 + (i&1)*4];
  e.x /= (d.x + 1e-9f); e.y /= (d.y + 1e-9f);
  e.z /= (d.z + 1e-9f); e.w /= (d.w + 1e-9f);
  ((float4*)attn)[i] = e;
}

/* ---- residual + LayerNorm (+ReLU), wave per row of 512; writes fp32 reps + bf16 hb ---- */
__global__ __launch_bounds__(256) void ln_kernel(const float* __restrict__ out_pre,
    const float* __restrict__ h_in, const float* __restrict__ gamma,
    const float* __restrict__ beta,
    float* __restrict__ outf, u16* __restrict__ hb, int do_relu){
  int wid  = (blockIdx.x*blockDim.x + threadIdx.x) >> 6;   /* row */
  int lane = threadIdx.x & 63;
  const float* xp = out_pre + (size_t)wid*512;
  const float* hp = h_in    + (size_t)wid*512;
  float x[8]; float sum = 0.f;
  for (int i=0;i<8;i++){ int c = lane + i*64; x[i] = xp[c] + hp[c]; sum += x[i]; }
  for (int o=32;o>0;o>>=1) sum += __shfl_xor(sum, o);
  float mu = sum * (1.f/512.f);
  float vs = 0.f;
  for (int i=0;i<8;i++){ float d = x[i]-mu; vs += d*d; }
  for (int o=32;o>0;o>>=1) vs += __shfl_xor(vs, o);
  float inv = rsqrtf(vs*(1.f/512.f) + 1e-5f);
  for (int i=0;i<8;i++){
    int c = lane + i*64;
    float y = (x[i]-mu)*inv*gamma[c] + beta[c];
    if (do_relu) y = fmaxf(y, 0.f);
    outf[(size_t)wid*512 + c] = y;
    hb  [(size_t)wid*512 + c] = f2bf(y);
  }
}

extern "C" void kernel_launch(void* const* d_in, const int* in_sizes, int n_in,
                              void* d_out, int out_size, void* d_ws, size_t ws_size,
                              hipStream_t stream){
  (void)in_sizes; (void)n_in; (void)out_size; (void)ws_size;
  const float* inp      = (const float*)d_in[0];
  const int* edge_len   = (const int*)d_in[2];
  const int* edge_index = (const int*)d_in[3];
  const int* relpos_e   = (const int*)d_in[4];
  const int* deprel_e   = (const int*)d_in[6];
  const int* deparc_e   = (const int*)d_in[7];
  const float* Wq = (const float*)d_in[14];
  const float* Wk = (const float*)d_in[15];
  const float* Wv = (const float*)d_in[16];
  const float* Wo = (const float*)d_in[17];
  const float* deprel_emb = (const float*)d_in[18];
  const float* deparc_emb = (const float*)d_in[19];
  const float* relpos_emb = (const float*)d_in[20];
  const float* ln_scale   = (const float*)d_in[21];
  const float* ln_bias    = (const float*)d_in[22];
  float* outp = (float*)d_out;

  /* ---- carve workspace (~89 MB) ---- */
  char* w = (char*)d_ws;
  auto carve = [&](size_t b)->char*{ char* p = w; w += (b + 255) & ~(size_t)255; return p; };
  u16* WT        = (u16*)carve((size_t)8*262144*2);
  int* bstart    = (int*)carve(32*4);
  int* deg       = (int*)carve((size_t)N_N*4);
  int* cursor    = (int*)carve((size_t)N_N*4);
  int* row_start = (int*)carve((size_t)(N_N+1)*4);
  int* csr_src   = (int*)carve((size_t)N_BE*4);
  int* csr_meta  = (int*)carve((size_t)N_BE*4);
  int* csr_f     = (int*)carve((size_t)N_BE*4);
  int* tgt_f     = (int*)carve((size_t)N_BE*4);
  u16* rel_table = (u16*)carve((size_t)N_COMBO*64*2);
  float* den_ws  = (float*)carve((size_t)N_N*8*4);
  u16* hb        = (u16*)carve((size_t)N_N*512*2);
  u16* qb        = (u16*)carve((size_t)N_N*512*2);   /* qb+kb alias out_pre (fp32) */
  u16* kb        = (u16*)carve((size_t)N_N*512*2);
  u16* vb        = (u16*)carve((size_t)N_N*512*2);
  u16* aggb      = (u16*)carve((size_t)N_N*512*2);
  float* out_pre = (float*)qb;   /* 32MB alias over qb+kb, dead by the time it's written */

  /* ---- per-call setup ---- */
  transpose_kernel<<<dim3(16,16,8), dim3(32,8), 0, stream>>>(Wq,Wk,Wv,Wo, WT);
  convert_kernel<<<dim3(8192), dim3(256), 0, stream>>>(inp, hb, N_N*512/4);
  zero_kernel<<<dim3(64),   dim3(256), 0, stream>>>((u32*)deg,    N_N);
  zero_kernel<<<dim3(64),   dim3(256), 0, stream>>>((u32*)cursor, N_N);
  zero_kernel<<<dim3(512),  dim3(256), 0, stream>>>((u32*)tgt_f,  N_BE);
  u32* attn_all = (u32*)(outp + (size_t)N_L*N_N*512);
  zero_kernel<<<dim3(8192), dim3(256), 0, stream>>>(attn_all, N_L*N_BE*N_H);
  bstart_kernel<<<dim3(1), dim3(1), 0, stream>>>(edge_len, bstart);
  count_kernel<<<dim3(N_BE/256), dim3(256), 0, stream>>>(edge_len, edge_index, deg);
  scan_kernel<<<dim3(1), dim3(1024), 0, stream>>>(deg, row_start);
  fill_kernel<<<dim3(N_BE/256), dim3(256), 0, stream>>>(edge_len, edge_index,
      relpos_e, deprel_e, deparc_e, bstart, row_start, cursor,
      csr_src, csr_meta, csr_f, tgt_f);

  /* ---- layers ---- */
  for (int l=0; l<N_L; l++){
    float* reps_out = outp + (size_t)l*N_N*512;
    float* attn_out = outp + (size_t)N_L*N_N*512 + (size_t)l*N_BE*N_H;
    const u16* WqT = WT + (0*2 + l)*262144;
    const u16* WkT = WT + (1*2 + l)*262144;
    const u16* WvT = WT + (2*2 + l)*262144;
    const u16* WoT = WT + (3*2 + l)*262144;

    rel_kernel<<<dim3((N_COMBO*64+255)/256), dim3(256), 0, stream>>>(
        deprel_emb + l*50*64, deparc_emb + l*3*64, relpos_emb + l*21*64, rel_table);

    gemm_kernel<false><<<dim3(4,128,3), dim3(256), 0, stream>>>(hb,
        WqT, WkT, WvT, (void*)qb, (void*)kb, (void*)vb);

    edge_attn_kernel<<<dim3(N_N/4), dim3(256), 0, stream>>>(qb, kb, vb,
        row_start, csr_src, csr_meta, csr_f, rel_table,
        den_ws, aggb, attn_out);

    rescale_kernel<<<dim3(N_BE*2/256), dim3(256), 0, stream>>>(attn_out, tgt_f, den_ws);

    gemm_kernel<true><<<dim3(4,128,1), dim3(256), 0, stream>>>(aggb,
        WoT, WoT, WoT, (void*)out_pre, (void*)out_pre, (void*)out_pre);

    ln_kernel<<<dim3(N_N/4), dim3(256), 0, stream>>>(out_pre,
        (l==0) ? inp : outp,            /* residual: inp or reps[0] */
        ln_scale + l*512, ln_bias + l*512, reps_out, hb, (l==0)?1:0);
  }
}

// Round 8
// 386.936 us; speedup vs baseline: 2.0377x; 1.0614x over previous
//
#include <hip/hip_runtime.h>

typedef unsigned short u16;
typedef unsigned int   u32;
typedef __attribute__((ext_vector_type(8))) short short8;
typedef __attribute__((ext_vector_type(4))) float floatx4;
typedef __attribute__((address_space(1))) const unsigned int glob_u32;
typedef __attribute__((address_space(3))) unsigned int lds_u32;

#define N_B  16
#define N_S  1024
#define N_E  8192
#define N_D  512
#define N_H  8
#define N_DK 64
#define N_L  2
#define N_N  (N_B*N_S)   /* 16384 */
#define N_BE (N_B*N_E)   /* 131072 */
#define N_COMBO 3150     /* 50*3*21 rel-combos */

__device__ __forceinline__ float bf2f(u16 u){ return __uint_as_float(((u32)u)<<16); }
__device__ __forceinline__ u16 f2bf(float f){
  u32 i = __float_as_uint(f);
  return (u16)((i + 0x7fffu + ((i>>16)&1u)) >> 16);
}

/* ---------------- generic zero ---------------- */
__global__ void zero_kernel(u32* __restrict__ p, int n){
  int i = blockIdx.x*blockDim.x + threadIdx.x;
  if (i < n) p[i] = 0;
}

/* ---------------- fp32 -> bf16 convert (4 elems/thread) ---------------- */
__global__ void convert_kernel(const float* __restrict__ in, u16* __restrict__ outp, int n4){
  int i = blockIdx.x*blockDim.x + threadIdx.x;
  if (i < n4){
    float4 f = ((const float4*)in)[i];
    u16 o[4] = { f2bf(f.x), f2bf(f.y), f2bf(f.z), f2bf(f.w) };
    ((uint2*)outp)[i] = *(uint2*)o;
  }
}

/* ---- transpose+convert the 8 weight matrices (512x512 fp32) to bf16 N x K ---- */
__global__ void transpose_kernel(const float* __restrict__ Wq, const float* __restrict__ Wk,
                                 const float* __restrict__ Wv, const float* __restrict__ Wo,
                                 u16* __restrict__ WT){
  __shared__ u16 tile[32][33];
  int z = blockIdx.z, wsel = z>>1, l = z&1;
  const float* in = (wsel==0?Wq: wsel==1?Wk: wsel==2?Wv:Wo) + l*262144;
  u16* outp = WT + z*262144;
  int bx = blockIdx.x*32, by = blockIdx.y*32;
  int tx = threadIdx.x, ty = threadIdx.y;           /* block (32,8) */
  for (int r=0;r<32;r+=8) tile[ty+r][tx] = f2bf(in[(by+ty+r)*512 + bx+tx]);
  __syncthreads();
  for (int r=0;r<32;r+=8) outp[(bx+ty+r)*512 + by+tx] = tile[tx][ty+r];
}

/* ---------------- ragged-edge prefix over batches ---------------- */
__global__ void bstart_kernel(const int* __restrict__ edge_len, int* __restrict__ bstart){
  if (threadIdx.x==0 && blockIdx.x==0){
    int s=0;
    for (int b=0;b<N_B;b++){ bstart[b]=s; s+=edge_len[b]; }
    bstart[N_B]=s;
  }
}

/* ---------------- in-degree count ---------------- */
__global__ void count_kernel(const int* __restrict__ edge_len, const int* __restrict__ edge_index,
                             int* __restrict__ deg){
  int idx = blockIdx.x*256 + threadIdx.x;           /* over B*E */
  int b = idx >> 13, e = idx & (N_E-1);
  if (e < edge_len[b]){
    int t = edge_index[idx*2+1] + b*N_S;
    atomicAdd(&deg[t], 1);
  }
}

/* ---------------- exclusive scan of degrees (N = 16384 = 1024*16) ---------------- */
__global__ void scan_kernel(const int* __restrict__ deg, int* __restrict__ row_start){
  __shared__ int sums[1024];
  int t = threadIdx.x;
  int base = t*16;
  int local[16]; int s = 0;
  for (int i=0;i<16;i++){ local[i] = s; s += deg[base+i]; }
  sums[t] = s; __syncthreads();
  for (int off=1; off<1024; off<<=1){
    int add = (t >= off) ? sums[t-off] : 0;
    __syncthreads();
    sums[t] += add;
    __syncthreads();
  }
  int prefix = (t>0) ? sums[t-1] : 0;
  for (int i=0;i<16;i++) row_start[base+i] = prefix + local[i];
  if (t==1023) row_start[N_N] = sums[1023];
}

/* ---- fill CSR: src / combo-meta / flat-edge-id into CSR order; also f->tgt map ---- */
__global__ void fill_kernel(const int* __restrict__ edge_len, const int* __restrict__ edge_index,
                            const int* __restrict__ relpos_e, const int* __restrict__ deprel_e,
                            const int* __restrict__ deparc_e, const int* __restrict__ bstart,
                            const int* __restrict__ row_start, int* __restrict__ cursor,
                            int* __restrict__ csr_src, int* __restrict__ csr_meta,
                            int* __restrict__ csr_f, int* __restrict__ tgt_f){
  int idx = blockIdx.x*256 + threadIdx.x;
  int b = idx >> 13, e = idx & (N_E-1);
  if (e < edge_len[b]){
    int f = bstart[b]+e;
    int s = edge_index[idx*2+0] + b*N_S;
    int t = edge_index[idx*2+1] + b*N_S;
    int pos = atomicAdd(&cursor[t], 1);
    int slot = row_start[t] + pos;
    csr_src[slot]  = s;
    csr_meta[slot] = deprel_e[idx] + 50*deparc_e[idx] + 150*relpos_e[idx];
    csr_f[slot]    = f;
    tgt_f[f]       = t;
  }
}

/* ---- per-layer rel table: rel_table[combo*64+d] = bf16(dre+dae+rpe) ---- */
__global__ void rel_kernel(const float* __restrict__ dre, const float* __restrict__ dae,
                           const float* __restrict__ rpe, u16* __restrict__ rel_table){
  int i = blockIdx.x*256 + threadIdx.x;     /* over 3150*64 */
  if (i < N_COMBO*64){
    int combo = i >> 6, d = i & 63;
    int dr = combo % 50, da = (combo/50) % 3, rp = combo/150;
    rel_table[i] = f2bf(dre[dr*64+d] + dae[da*64+d] + rpe[rp*64+d]);
  }
}

/* ---- MFMA GEMM v2: global_load_lds staging + XCD-affinity block swizzle ----
   C[M,512] = A[M,512] @ W ; Bt is W^T bf16 (N x K row-major).
   128x128x32 tiles; LDS tiles are contiguous [128][32] (no pad: lane-scatter
   rule of global_load_lds). XCD = linear_block&7 owns a contiguous 16-ytile
   stripe of A (2MB) across all x,z -> A stays L2-resident per XCD. */
template<bool F32OUT>
__global__ __launch_bounds__(256) void gemm_kernel(const u16* __restrict__ A,
    const u16* __restrict__ B0, const u16* __restrict__ B1, const u16* __restrict__ B2,
    void* __restrict__ C0, void* __restrict__ C1, void* __restrict__ C2){
  __shared__ __align__(16) u16 As[128*32];
  __shared__ __align__(16) u16 Bs[128*32];
  int tid  = threadIdx.x;
  int lane = tid & 63, wave = tid >> 6;

  u32 b    = blockIdx.x + gridDim.x*(blockIdx.y + gridDim.y*blockIdx.z);
  u32 xcd  = b & 7, slot = b >> 3;
  u32 ypg  = gridDim.y >> 3;                 /* y-tiles per XCD */
  u32 my   = xcd*ypg + slot % ypg;
  u32 rest = slot / ypg;
  u32 mx   = rest % gridDim.x;
  u32 mz   = rest / gridDim.x;
  const u16* Bt = (mz==0) ? B0 : (mz==1) ? B1 : B2;
  void* C       = (mz==0) ? C0 : (mz==1) ? C1 : C2;
  int tileM = my * 128, tileN = mx * 128;

  /* staging: chunk c in [0,512) covers tile bytes [c*16,+16); row=c>>2, cc=c&3.
     call r in {0,1}: this wave stages chunks [r*256+wave*64, +64). */
  int c0 = wave*64 + lane, c1 = c0 + 256;
  int row0 = c0 >> 2, cc0 = c0 & 3;
  int row1 = c1 >> 2, cc1 = c1 & 3;
  const u16* gA0 = &A [(size_t)(tileM+row0)*512 + cc0*8];
  const u16* gA1 = &A [(size_t)(tileM+row1)*512 + cc1*8];
  const u16* gB0 = &Bt[(size_t)(tileN+row0)*512 + cc0*8];
  const u16* gB1 = &Bt[(size_t)(tileN+row1)*512 + cc1*8];
  u16* lA0 = As + wave*512;          /* chunkbase*8 u16 */
  u16* lA1 = As + 2048 + wave*512;
  u16* lB0 = Bs + wave*512;
  u16* lB1 = Bs + 2048 + wave*512;

  int wm = wave >> 1, wn = wave & 1;
  int quad = lane >> 4, l16 = lane & 15;

  floatx4 acc[4][4];
  for (int i=0;i<4;i++) for (int j=0;j<4;j++) acc[i][j] = (floatx4){0.f,0.f,0.f,0.f};

  for (int k0 = 0; k0 < 512; k0 += 32){
    __syncthreads();
    __builtin_amdgcn_global_load_lds((glob_u32*)(gA0 + k0), (lds_u32*)lA0, 16, 0, 0);
    __builtin_amdgcn_global_load_lds((glob_u32*)(gA1 + k0), (lds_u32*)lA1, 16, 0, 0);
    __builtin_amdgcn_global_load_lds((glob_u32*)(gB0 + k0), (lds_u32*)lB0, 16, 0, 0);
    __builtin_amdgcn_global_load_lds((glob_u32*)(gB1 + k0), (lds_u32*)lB1, 16, 0, 0);
    __syncthreads();                       /* drains vmcnt: LDS tile visible */
    short8 af[4], bfr[4];
    for (int i=0;i<4;i++) af [i] = *(const short8*)&As[(wm*64 + i*16 + l16)*32 + quad*8];
    for (int j=0;j<4;j++) bfr[j] = *(const short8*)&Bs[(wn*64 + j*16 + l16)*32 + quad*8];
    for (int i=0;i<4;i++)
      for (int j=0;j<4;j++)
        acc[i][j] = __builtin_amdgcn_mfma_f32_16x16x32_bf16(af[i], bfr[j], acc[i][j], 0,0,0);
  }
  /* C/D layout: col = lane&15, row = quad*4 + reg */
  for (int i=0;i<4;i++)
    for (int j=0;j<4;j++)
      for (int r=0;r<4;r++){
        int row = tileM + wm*64 + i*16 + quad*4 + r;
        int col = tileN + wn*64 + j*16 + l16;
        if (F32OUT) ((float*)C)[(size_t)row*512 + col] = acc[i][j][r];
        else        ((u16*) C)[(size_t)row*512 + col] = f2bf(acc[i][j][r]);
      }
}

/* ---- edge attention v4: single pass, unroll-2, rel_table, no epilogue loop.
   One wave per node, lane = (head h=lane>>3, dims d0=(lane&7)*8). Writes raw e
   to attn_out and denominator s to den_ws; rescale_kernel normalizes. ---- */
__global__ __launch_bounds__(256) void edge_attn_kernel(
    const u16* __restrict__ q, const u16* __restrict__ k, const u16* __restrict__ v,
    const int* __restrict__ row_start,
    const int* __restrict__ csr_src, const int* __restrict__ csr_meta,
    const int* __restrict__ csr_f, const u16* __restrict__ rel_table,
    float* __restrict__ den_ws,
    u16* __restrict__ agg, float* __restrict__ attn_out){
  int bid = blockIdx.x;
  int lb  = (bid & 7) * (gridDim.x >> 3) + (bid >> 3);   /* XCD-contiguous remap */
  int t    = lb*4 + (threadIdx.x >> 6);                  /* node */
  int lane = threadIdx.x & 63;
  int h  = lane >> 3;
  int d0 = (lane & 7) * 8;
  int rs = row_start[t], re = row_start[t+1];

  float qv[8];
  {
    uint4 qraw = *(const uint4*)&q[(size_t)t*512 + h*64 + d0];
    const u16* qp = (const u16*)&qraw;
    for (int j=0;j<8;j++) qv[j] = bf2f(qp[j]);
  }

  float s = 0.f;
  float acc[8] = {0.f,0.f,0.f,0.f,0.f,0.f,0.f,0.f};
  int idx = rs;
  for (; idx + 1 < re; idx += 2){
    int sn0 = csr_src[idx],   mi0 = csr_meta[idx],   f0 = csr_f[idx];
    int sn1 = csr_src[idx+1], mi1 = csr_meta[idx+1], f1 = csr_f[idx+1];
    uint4 k0 = *(const uint4*)&k[(size_t)sn0*512 + h*64 + d0];
    uint4 v0 = *(const uint4*)&v[(size_t)sn0*512 + h*64 + d0];
    uint4 r0 = *(const uint4*)&rel_table[mi0*64 + d0];
    uint4 k1 = *(const uint4*)&k[(size_t)sn1*512 + h*64 + d0];
    uint4 v1 = *(const uint4*)&v[(size_t)sn1*512 + h*64 + d0];
    uint4 r1 = *(const uint4*)&rel_table[mi1*64 + d0];
    const u16 *kp0=(const u16*)&k0, *vp0=(const u16*)&v0, *rp0=(const u16*)&r0;
    const u16 *kp1=(const u16*)&k1, *vp1=(const u16*)&v1, *rp1=(const u16*)&r1;
    float rel0[8], rel1[8];
    for (int j=0;j<8;j++){ rel0[j]=bf2f(rp0[j]); rel1[j]=bf2f(rp1[j]); }
    float p0 = 0.f, p1 = 0.f;
    for (int j=0;j<8;j++){ p0 += qv[j]*(bf2f(kp0[j])+rel0[j]);
                           p1 += qv[j]*(bf2f(kp1[j])+rel1[j]); }
    p0 += __shfl_xor(p0,1); p1 += __shfl_xor(p1,1);
    p0 += __shfl_xor(p0,2); p1 += __shfl_xor(p1,2);
    p0 += __shfl_xor(p0,4); p1 += __shfl_xor(p1,4);
    float e0 = __expf(p0*0.125f), e1 = __expf(p1*0.125f);
    if ((lane & 7) == 0){
      attn_out[(size_t)f0*8 + h] = e0;
      attn_out[(size_t)f1*8 + h] = e1;
    }
    s += e0 + e1;
    for (int j=0;j<8;j++) acc[j] += e0*(bf2f(vp0[j])+rel0[j]) + e1*(bf2f(vp1[j])+rel1[j]);
  }
  if (idx < re){
    int sn0 = csr_src[idx], mi0 = csr_meta[idx], f0 = csr_f[idx];
    uint4 k0 = *(const uint4*)&k[(size_t)sn0*512 + h*64 + d0];
    uint4 v0 = *(const uint4*)&v[(size_t)sn0*512 + h*64 + d0];
    uint4 r0 = *(const uint4*)&rel_table[mi0*64 + d0];
    const u16 *kp0=(const u16*)&k0, *vp0=(const u16*)&v0, *rp0=(const u16*)&r0;
    float p0 = 0.f;
    for (int j=0;j<8;j++) p0 += qv[j]*(bf2f(kp0[j])+bf2f(rp0[j]));
    p0 += __shfl_xor(p0,1);
    p0 += __shfl_xor(p0,2);
    p0 += __shfl_xor(p0,4);
    float e0 = __expf(p0*0.125f);
    if ((lane & 7) == 0) attn_out[(size_t)f0*8 + h] = e0;
    s += e0;
    for (int j=0;j<8;j++) acc[j] += e0*(bf2f(vp0[j])+bf2f(rp0[j]));
  }
  float invden = 1.f / (s + 1e-9f);
  if ((lane & 7) == 0) den_ws[t*8 + h] = s;

  u16 ob[8];
  for (int j=0;j<8;j++) ob[j] = f2bf(acc[j] * invden);
  *(uint4*)&agg[(size_t)t*512 + h*64 + d0] = *(uint4*)ob;
}

/* ---- rescale: alpha = e / (den[tgt]+1e-9), float4 per thread over BE*8 floats ---- */
__global__ void rescale_kernel(float* __restrict__ attn, const int* __restrict__ tgt_f,
                               const float* __restrict__ den_ws){
  int i = blockIdx.x*256 + threadIdx.x;     /* over N_BE*2 float4s */
  int f = i >> 1;
  int t = tgt_f[f];
  float4 e = ((float4*)attn)[i];
  float4 d = *(const float4*)&den_ws[t*8 + (i&1)*4];
  e.x /= (d.x + 1e-9f); e.y /= (d.y + 1e-9f);
  e.z /= (d.z + 1e-9f); e.w /= (d.w + 1e-9f);
  ((float4*)attn)[i] = e;
}

/* ---- residual + LayerNorm (+ReLU), wave per row of 512; writes fp32 reps + bf16 hb ---- */
__global__ __launch_bounds__(256) void ln_kernel(const float* __restrict__ out_pre,
    const float* __restrict__ h_in, const float* __restrict__ gamma,
    const float* __restrict__ beta,
    float* __restrict__ outf, u16* __restrict__ hb, int do_relu){
  int wid  = (blockIdx.x*blockDim.x + threadIdx.x) >> 6;   /* row */
  int lane = threadIdx.x & 63;
  const float* xp = out_pre + (size_t)wid*512;
  const float* hp = h_in    + (size_t)wid*512;
  float x[8]; float sum = 0.f;
  for (int i=0;i<8;i++){ int c = lane + i*64; x[i] = xp[c] + hp[c]; sum += x[i]; }
  for (int o=32;o>0;o>>=1) sum += __shfl_xor(sum, o);
  float mu = sum * (1.f/512.f);
  float vs = 0.f;
  for (int i=0;i<8;i++){ float d = x[i]-mu; vs += d*d; }
  for (int o=32;o>0;o>>=1) vs += __shfl_xor(vs, o);
  float inv = rsqrtf(vs*(1.f/512.f) + 1e-5f);
  for (int i=0;i<8;i++){
    int c = lane + i*64;
    float y = (x[i]-mu)*inv*gamma[c] + beta[c];
    if (do_relu) y = fmaxf(y, 0.f);
    outf[(size_t)wid*512 + c] = y;
    hb  [(size_t)wid*512 + c] = f2bf(y);
  }
}

extern "C" void kernel_launch(void* const* d_in, const int* in_sizes, int n_in,
                              void* d_out, int out_size, void* d_ws, size_t ws_size,
                              hipStream_t stream){
  (void)in_sizes; (void)n_in; (void)out_size; (void)ws_size;
  const float* inp      = (const float*)d_in[0];
  const int* edge_len   = (const int*)d_in[2];
  const int* edge_index = (const int*)d_in[3];
  const int* relpos_e   = (const int*)d_in[4];
  const int* deprel_e   = (const int*)d_in[6];
  const int* deparc_e   = (const int*)d_in[7];
  const float* Wq = (const float*)d_in[14];
  const float* Wk = (const float*)d_in[15];
  const float* Wv = (const float*)d_in[16];
  const float* Wo = (const float*)d_in[17];
  const float* deprel_emb = (const float*)d_in[18];
  const float* deparc_emb = (const float*)d_in[19];
  const float* relpos_emb = (const float*)d_in[20];
  const float* ln_scale   = (const float*)d_in[21];
  const float* ln_bias    = (const float*)d_in[22];
  float* outp = (float*)d_out;

  /* ---- carve workspace (~89 MB) ---- */
  char* w = (char*)d_ws;
  auto carve = [&](size_t b)->char*{ char* p = w; w += (b + 255) & ~(size_t)255; return p; };
  u16* WT        = (u16*)carve((size_t)8*262144*2);
  int* bstart    = (int*)carve(32*4);
  int* deg       = (int*)carve((size_t)N_N*4);
  int* cursor    = (int*)carve((size_t)N_N*4);
  int* row_start = (int*)carve((size_t)(N_N+1)*4);
  int* csr_src   = (int*)carve((size_t)N_BE*4);
  int* csr_meta  = (int*)carve((size_t)N_BE*4);
  int* csr_f     = (int*)carve((size_t)N_BE*4);
  int* tgt_f     = (int*)carve((size_t)N_BE*4);
  u16* rel_table = (u16*)carve((size_t)N_COMBO*64*2);
  float* den_ws  = (float*)carve((size_t)N_N*8*4);
  u16* hb        = (u16*)carve((size_t)N_N*512*2);
  u16* qb        = (u16*)carve((size_t)N_N*512*2);   /* qb+kb alias out_pre (fp32) */
  u16* kb        = (u16*)carve((size_t)N_N*512*2);
  u16* vb        = (u16*)carve((size_t)N_N*512*2);
  u16* aggb      = (u16*)carve((size_t)N_N*512*2);
  float* out_pre = (float*)qb;   /* 32MB alias over qb+kb, dead by the time it's written */

  /* ---- per-call setup ---- */
  transpose_kernel<<<dim3(16,16,8), dim3(32,8), 0, stream>>>(Wq,Wk,Wv,Wo, WT);
  convert_kernel<<<dim3(8192), dim3(256), 0, stream>>>(inp, hb, N_N*512/4);
  zero_kernel<<<dim3(64),   dim3(256), 0, stream>>>((u32*)deg,    N_N);
  zero_kernel<<<dim3(64),   dim3(256), 0, stream>>>((u32*)cursor, N_N);
  zero_kernel<<<dim3(512),  dim3(256), 0, stream>>>((u32*)tgt_f,  N_BE);
  u32* attn_all = (u32*)(outp + (size_t)N_L*N_N*512);
  zero_kernel<<<dim3(8192), dim3(256), 0, stream>>>(attn_all, N_L*N_BE*N_H);
  bstart_kernel<<<dim3(1), dim3(1), 0, stream>>>(edge_len, bstart);
  count_kernel<<<dim3(N_BE/256), dim3(256), 0, stream>>>(edge_len, edge_index, deg);
  scan_kernel<<<dim3(1), dim3(1024), 0, stream>>>(deg, row_start);
  fill_kernel<<<dim3(N_BE/256), dim3(256), 0, stream>>>(edge_len, edge_index,
      relpos_e, deprel_e, deparc_e, bstart, row_start, cursor,
      csr_src, csr_meta, csr_f, tgt_f);

  /* ---- layers ---- */
  for (int l=0; l<N_L; l++){
    float* reps_out = outp + (size_t)l*N_N*512;
    float* attn_out = outp + (size_t)N_L*N_N*512 + (size_t)l*N_BE*N_H;
    const u16* WqT = WT + (0*2 + l)*262144;
    const u16* WkT = WT + (1*2 + l)*262144;
    const u16* WvT = WT + (2*2 + l)*262144;
    const u16* WoT = WT + (3*2 + l)*262144;

    rel_kernel<<<dim3((N_COMBO*64+255)/256), dim3(256), 0, stream>>>(
        deprel_emb + l*50*64, deparc_emb + l*3*64, relpos_emb + l*21*64, rel_table);

    gemm_kernel<false><<<dim3(4,128,3), dim3(256), 0, stream>>>(hb,
        WqT, WkT, WvT, (void*)qb, (void*)kb, (void*)vb);

    edge_attn_kernel<<<dim3(N_N/4), dim3(256), 0, stream>>>(qb, kb, vb,
        row_start, csr_src, csr_meta, csr_f, rel_table,
        den_ws, aggb, attn_out);

    rescale_kernel<<<dim3(N_BE*2/256), dim3(256), 0, stream>>>(attn_out, tgt_f, den_ws);

    gemm_kernel<true><<<dim3(4,128,1), dim3(256), 0, stream>>>(aggb,
        WoT, WoT, WoT, (void*)out_pre, (void*)out_pre, (void*)out_pre);

    ln_kernel<<<dim3(N_N/4), dim3(256), 0, stream>>>(out_pre,
        (l==0) ? inp : outp,            /* residual: inp or reps[0] */
        ln_scale + l*512, ln_bias + l*512, reps_out, hb, (l==0)?1:0);
  }
}